// Round 14
// baseline (985.401 us; speedup 1.0000x reference)
//
#include <hip/hip_runtime.h>
#include <hip/hip_fp16.h>
#include <math.h>

typedef _Float16 half_t;
typedef __attribute__((ext_vector_type(8))) _Float16 f16x8;  // MFMA A/B frag
typedef __attribute__((ext_vector_type(4))) float   f32x4;   // MFMA C/D frag
typedef __attribute__((ext_vector_type(4))) float   float4v;

#define IN_F   1536
#define HID    640
#define OUT_F  10
#define NBATCH 65536

#define SB() __builtin_amdgcn_sched_barrier(0)

// ---------- helpers ----------

__device__ __forceinline__ void gll16(const void* g, const void* l) {
    __builtin_amdgcn_global_load_lds(
        (const __attribute__((address_space(1))) unsigned*)g,
        (__attribute__((address_space(3))) unsigned*)l, 16, 0, 0);
}

// exact-GELU via A&S 7.1.26 erf poly (|eps|<=1.5e-7, noise vs f16 rounding)
__device__ __forceinline__ float gelu_fast(float z) {
    float x  = 0.70710678118654752f * z;
    float ax = fabsf(x);
    float t  = 1.0f / (1.0f + 0.3275911f * ax);
    float p  = t * (0.254829592f +
               t * (-0.284496736f +
               t * (1.421413741f +
               t * (-1.453152027f +
               t * 1.061405429f))));
    float e  = __expf(-ax * ax);
    float er = 1.0f - p * e;
    er = (x < 0.0f) ? -er : er;
    return 0.5f * z * (1.0f + er);
}

// ---------- prep ----------

__global__ void k_detect(const unsigned* __restrict__ m, int nDwords, int* flags) {
    int f = 0, g = 0;
    for (int i = blockIdx.x * blockDim.x + threadIdx.x; i < nDwords;
         i += gridDim.x * blockDim.x) {
        unsigned d = m[i];
        f |= (d == 0x3F800000u);
        g |= (d != 0u) & (d != 1u) & (d != 0x3F800000u);
    }
    if (f) atomicOr(&flags[0], 1);
    if (g) atomicOr(&flags[1], 1);
}

__device__ __forceinline__ bool mask_at(const void* mask, int i, int isB, int isF) {
    if (isB) return ((const unsigned char*)mask)[i] != 0;
    if (isF) return ((const float*)mask)[i] != 0.0f;
    return ((const int*)mask)[i] != 0;
}

__global__ void k_mask_all(const float* __restrict__ W1, const float* __restrict__ W2,
                           const float* __restrict__ W3,
                           const void* __restrict__ m1, const void* __restrict__ m2,
                           const void* __restrict__ m3,
                           half_t* __restrict__ W1h, half_t* __restrict__ W2h,
                           float* __restrict__ W3m, const int* __restrict__ flags) {
    const int isB = flags[1], isF = flags[0];
    const int N1 = HID * IN_F, N2 = HID * HID, N3 = OUT_F * HID;
    const int NT = N1 + N2 + N3;
    for (int i = blockIdx.x * blockDim.x + threadIdx.x; i < NT;
         i += gridDim.x * blockDim.x) {
        if (i < N1) {
            W1h[i] = mask_at(m1, i, isB, isF) ? (half_t)W1[i] : (half_t)0.0f;
        } else if (i < N1 + N2) {
            int j = i - N1;
            W2h[j] = mask_at(m2, j, isB, isF) ? (half_t)W2[j] : (half_t)0.0f;
        } else {
            int j = i - N1 - N2;
            W3m[j] = mask_at(m3, j, isB, isF) ? W3[j] : 0.0f;
        }
    }
}

// ---------- GEMM1: BM=128, BN=320, acc=80, 2 blocks/CU, depth-2 ring ----------
// h1[m][n] = gelu( sum_k x[m][k] * W1[n][k] ), f16 out.
// 512 thr = 8 waves (2m x 4n of 64x80), acc[4][5]=80 VGPR, LB(512,4) -> <=128
// VGPR, 2 blocks/CU (the duty-cycle lever: VMEM service ~11 B/cyc per block).
// LDS: 2 slabs x (A f32 [128][128B] 16KB + B pair-packed 20KB) = 72KB.
// Two-barrier counted-vmcnt ring (R9-proven): entry vmcnt(cls) retires L(ks)
// keeping L(ks+1); READY barrier; ds_read frags; lgkm(0); SB; CONSUMED
// barrier; STAGE(ks+2)->slab ks%2; MFMA.
// Per-wave-class ops/tile: waves 0-3 (t<256): 2A+3B=5; waves 4-7: 2A+2B=4.
__global__ __launch_bounds__(512, 4) void gemm1_tall(
    const float* __restrict__ Ain, const half_t* __restrict__ Bw,
    half_t* __restrict__ Cout) {
    constexpr int K    = IN_F;
    constexpr int NK   = K / 32;                     // 48
    constexpr int SLAB = 16384 + 20480;              // A 16KB + B 20KB
    __shared__ __align__(16) char lds[2 * SLAB];     // 72KB -> 2 blocks/CU

    const int t = threadIdx.x, lane = t & 63, wid = t >> 6;
    const int wr = wid >> 2, wc = wid & 3;

    // XCD-bijective swizzle; nwg = 1024 = 8*128, n-fastest (2 blocks/panel).
    const int q       = (int)gridDim.x >> 3;
    const int logical = ((int)blockIdx.x & 7) * q + ((int)blockIdx.x >> 3);
    const int mb = logical >> 1, nbk = logical & 1;
    const long mBase = (long)mb * 128;
    const int  n0    = nbk * 320;

    const int rr = lane & 15, k8 = lane >> 4;

    // fragment read bases: A [128][128B] 8-slot XOR; B pair-packed
    int aRd[4], bBase;
    {
#pragma unroll
        for (int mf = 0; mf < 4; ++mf) {
            const int row = wr * 64 + mf * 16 + rr;
            aRd[mf] = row * 128 + (((2 * k8) ^ (row & 7)) << 4);
        }
        const int nrow = wc * 80 + rr, lnb = nrow >> 1;
        bBase = 16384 + lnb * 128 +
                ((((((nrow & 1) << 2) | k8)) ^ (lnb & 7)) << 4);
    }

    // staging sources (inverse-swizzled), linear gll dests
    // A: 2 ops, o=(t+r*512)*16 -> row=(t>>3)+64r, slot=t&7, kq=slot^(row&7)
    //    (64&7==0 -> same kq both ops)
    const float* srcAf;
    {
        const int row = t >> 3, kq = (t & 7) ^ ((t >> 3) & 7);
        srcAf = Ain + (mBase + row) * (long)K + kq * 4;
    }
    // B: ops r=0,1 all thr + r=2 for t<256; line=(t>>3)+64r, orig=(t&7)^(line&7)
    //    (64&7==0 -> same orig), nrow=2*line+(orig>>2), kq=orig&3
    const half_t* srcB;
    {
        const int line = t >> 3, orig = (t & 7) ^ (line & 7);
        const int nrow = 2 * line + (orig >> 2), kq = orig & 3;
        srcB = Bw + (size_t)(n0 + nrow) * K + kq * 8;
    }

    auto STAGE = [&](int k, int sb) {
        const size_t ko = (size_t)k * 32;
#pragma unroll
        for (int r = 0; r < 2; ++r)
            gll16(srcAf + ko + (size_t)r * 64 * K,
                  &lds[sb + (t + r * 512) * 16]);
#pragma unroll
        for (int r = 0; r < 2; ++r)
            gll16(srcB + ko + (size_t)r * 128 * K,
                  &lds[sb + 16384 + (t + r * 512) * 16]);
        if (t < 256)
            gll16(srcB + ko + (size_t)2 * 128 * K,
                  &lds[sb + 16384 + (t + 1024) * 16]);
    };

    f32x4 acc[4][5];
#pragma unroll
    for (int mf = 0; mf < 4; ++mf)
#pragma unroll
        for (int nf = 0; nf < 5; ++nf) {
            f32x4 z = {0.f, 0.f, 0.f, 0.f};
            acc[mf][nf] = z;
        }

    STAGE(0, 0); SB();
    STAGE(1, SLAB); SB();

    for (int ks = 0; ks < NK; ++ks) {
        const int cb = (ks & 1) * SLAB;
        if (ks + 1 < NK) {
            if (wid < 4) asm volatile("s_waitcnt vmcnt(5)" ::: "memory");
            else         asm volatile("s_waitcnt vmcnt(4)" ::: "memory");
        } else {
            asm volatile("s_waitcnt vmcnt(0)" ::: "memory");
        }
        __builtin_amdgcn_s_barrier();                 // READY(ks)
        f16x8 bv[5];
#pragma unroll
        for (int nf = 0; nf < 5; ++nf)
            bv[nf] = *(const f16x8*)(&lds[cb + bBase + nf * 1024]);
        f16x8 av[4];
#pragma unroll
        for (int mf = 0; mf < 4; ++mf) {
            float4v alo = *(const float4v*)(&lds[cb + aRd[mf]]);
            float4v ahi = *(const float4v*)(&lds[cb + (aRd[mf] ^ 16)]);
            f16x8 h;
#pragma unroll
            for (int i = 0; i < 4; ++i) {
                h[i]     = (half_t)alo[i];
                h[i + 4] = (half_t)ahi[i];
            }
            av[mf] = h;
        }
        asm volatile("s_waitcnt lgkmcnt(0)" ::: "memory");
        SB();                                          // rule 18
        __builtin_amdgcn_s_barrier();                  // CONSUMED(ks)
        if (ks + 2 < NK) { STAGE(ks + 2, cb); SB(); }
#pragma unroll
        for (int mf = 0; mf < 4; ++mf)
#pragma unroll
            for (int nf = 0; nf < 5; ++nf)
                acc[mf][nf] = __builtin_amdgcn_mfma_f32_16x16x32_f16(
                    av[mf], bv[nf], acc[mf][nf], 0, 0, 0);
    }

    // epilogue: C/D frag col=lane&15, row=(lane>>4)*4+j
    const int crow0 = (lane >> 4) * 4;
    const int ccol  = lane & 15;
#pragma unroll
    for (int mf = 0; mf < 4; ++mf)
#pragma unroll
        for (int nf = 0; nf < 5; ++nf)
#pragma unroll
            for (int j = 0; j < 4; ++j) {
                const long row = mBase + wr * 64 + mf * 16 + crow0 + j;
                const int  col = n0 + wc * 80 + nf * 16 + ccol;
                Cout[row * HID + col] = (half_t)gelu_fast(acc[mf][nf][j]);
            }
}

// ---------- GEMM2 (+ fused layer 3), R13-proven, unchanged ----------
// BM=256, BN=320, BK=32, 8 waves, acc[8][5]=160, 3-slab single-barrier ring.
template <int K>
__global__ __launch_bounds__(512, 2) void gemm2_fused(
    const half_t* __restrict__ Ain, const half_t* __restrict__ Bw,
    const float* __restrict__ W3, float* __restrict__ Pout) {
    constexpr int NK     = K / 32;                    // 20
    constexpr int ABYTES = 16384;
    constexpr int SLAB   = ABYTES + 20480;
    __shared__ __align__(16) char lds[3 * SLAB];      // 108KB

    const int t = threadIdx.x, lane = t & 63, wid = t >> 6;
    const int wr = wid >> 2, wc = wid & 3;

    const int q       = (int)gridDim.x >> 3;
    const int logical = ((int)blockIdx.x & 7) * q + ((int)blockIdx.x >> 3);
    const int mb = logical >> 1, nbk = logical & 1;
    const long mBase = (long)mb * 256;
    const int  n0    = nbk * 320;

    const int rr = lane & 15, k8 = lane >> 4;

    int aBase0 = 0, bBase = 0;
    {
        const int row = wr * 128 + rr, ln = row >> 1;
        aBase0 = ln * 128 + ((((((row & 1) << 2) | k8)) ^ (ln & 7)) << 4);
        const int nrow = wc * 80 + rr, lnb = nrow >> 1;
        bBase = ABYTES + lnb * 128 +
                ((((((nrow & 1) << 2) | k8)) ^ (lnb & 7)) << 4);
    }

    const half_t* srcAh;
    {
        const int line = t >> 3, orig = (t & 7) ^ (line & 7);
        const int row = 2 * line + (orig >> 2), kq = orig & 3;
        srcAh = Ain + (mBase + row) * (long)K + kq * 8;
    }
    const half_t* srcB;
    {
        const int line = t >> 3, orig = (t & 7) ^ (line & 7);
        const int nrow = 2 * line + (orig >> 2), kq = orig & 3;
        srcB = Bw + (size_t)(n0 + nrow) * K + kq * 8;
    }

    auto STAGE = [&](int k, int sb) {
        const size_t ko = (size_t)k * 32;
#pragma unroll
        for (int r = 0; r < 2; ++r)
            gll16(srcAh + ko + (size_t)r * 128 * K,
                  &lds[sb + (t + r * 512) * 16]);
#pragma unroll
        for (int r = 0; r < 2; ++r)
            gll16(srcB + ko + (size_t)r * 128 * K,
                  &lds[sb + ABYTES + (t + r * 512) * 16]);
        if (t < 256)
            gll16(srcB + ko + (size_t)2 * 128 * K,
                  &lds[sb + ABYTES + (t + 1024) * 16]);
    };

    f32x4 acc[8][5];
#pragma unroll
    for (int mf = 0; mf < 8; ++mf)
#pragma unroll
        for (int nf = 0; nf < 5; ++nf) {
            f32x4 z = {0.f, 0.f, 0.f, 0.f};
            acc[mf][nf] = z;
        }

    STAGE(0, 0); SB();
    STAGE(1, SLAB); SB();

    for (int ks = 0; ks < NK; ++ks) {
        if (ks + 1 < NK) {
            if (wid < 4) asm volatile("s_waitcnt vmcnt(5)" ::: "memory");
            else         asm volatile("s_waitcnt vmcnt(4)" ::: "memory");
        } else {
            asm volatile("s_waitcnt vmcnt(0)" ::: "memory");
        }
        __builtin_amdgcn_s_barrier();
        const int cb = (ks % 3) * SLAB;
        if (ks + 2 < NK) { STAGE(ks + 2, ((ks + 2) % 3) * SLAB); SB(); }

        f16x8 bv[5];
#pragma unroll
        for (int nf = 0; nf < 5; ++nf)
            bv[nf] = *(const f16x8*)(&lds[cb + bBase + nf * 1024]);
        f16x8 av[8];
#pragma unroll
        for (int mf = 0; mf < 8; ++mf)
            av[mf] = *(const f16x8*)(&lds[cb + aBase0 + mf * 1024]);
#pragma unroll
        for (int mf = 0; mf < 8; ++mf)
#pragma unroll
            for (int nf = 0; nf < 5; ++nf)
                acc[mf][nf] = __builtin_amdgcn_mfma_f32_16x16x32_f16(
                    av[mf], bv[nf], acc[mf][nf], 0, 0, 0);
    }

    // fused layer 3 epilogue (R13-proven)
    const int crow0 = (lane >> 4) * 4;
    const int ccol  = lane & 15;
    float w3[OUT_F][5];
#pragma unroll
    for (int o = 0; o < OUT_F; ++o)
#pragma unroll
        for (int nf = 0; nf < 5; ++nf)
            w3[o][nf] = W3[o * HID + n0 + wc * 80 + nf * 16 + ccol];
    float* slice = Pout + (size_t)(nbk * 4 + wc) * NBATCH * OUT_F;
#pragma unroll
    for (int mf = 0; mf < 8; ++mf)
#pragma unroll
        for (int j = 0; j < 4; ++j) {
            float p[OUT_F];
#pragma unroll
            for (int o = 0; o < OUT_F; ++o) p[o] = 0.f;
#pragma unroll
            for (int nf = 0; nf < 5; ++nf) {
                const float v = gelu_fast(acc[mf][nf][j]);
#pragma unroll
                for (int o = 0; o < OUT_F; ++o) p[o] += v * w3[o][nf];
            }
#pragma unroll
            for (int mask = 1; mask < 16; mask <<= 1)
#pragma unroll
                for (int o = 0; o < OUT_F; ++o)
                    p[o] += __shfl_xor(p[o], mask);
            float v = 0.f;
#pragma unroll
            for (int o = 0; o < OUT_F; ++o) v = (ccol == o) ? p[o] : v;
            const long row = mBase + wr * 128 + mf * 16 + crow0 + j;
            if (ccol < OUT_F) slice[row * OUT_F + ccol] = v;
        }
}

// ---------- final: out = sum of 8 partial slices ----------
__global__ void k_final(const float* __restrict__ P, float* __restrict__ out) {
    const int n = NBATCH * OUT_F;
    for (int i = blockIdx.x * blockDim.x + threadIdx.x; i < n;
         i += gridDim.x * blockDim.x) {
        float s0 = P[i]                 + P[(size_t)1 * n + i];
        float s1 = P[(size_t)2 * n + i] + P[(size_t)3 * n + i];
        float s2 = P[(size_t)4 * n + i] + P[(size_t)5 * n + i];
        float s3 = P[(size_t)6 * n + i] + P[(size_t)7 * n + i];
        out[i] = (s0 + s1) + (s2 + s3);
    }
}

// ---------- launch ----------

extern "C" void kernel_launch(void* const* d_in, const int* in_sizes, int n_in,
                              void* d_out, int out_size, void* d_ws, size_t ws_size,
                              hipStream_t stream) {
    const float* x  = (const float*)d_in[0];
    const float* W1 = (const float*)d_in[1];
    const float* W2 = (const float*)d_in[2];
    const float* W3 = (const float*)d_in[3];
    const void*  m1 = d_in[4];
    const void*  m2 = d_in[5];
    const void*  m3 = d_in[6];
    float* out = (float*)d_out;

    char* ws = (char*)d_ws;
    int*    flags = (int*)ws;
    half_t* W1h = (half_t*)(ws + 256);                      // 640*1536*2
    half_t* W2h = (half_t*)(ws + 256 + 1966080);            // 640*640*2
    float*  W3m = (float*)(ws + 256 + 1966080 + 819200);    // 25600
    half_t* h1  = (half_t*)(ws + 256 + 1966080 + 819200 + 25600);
    float*  Pp  = (float*)((char*)h1 + (size_t)NBATCH * HID * 2);  // 8*655360*4

    hipMemsetAsync(flags, 0, 8, stream);
    k_detect<<<64, 256, 0, stream>>>((const unsigned*)m1, 65536, flags);
    k_mask_all<<<1024, 256, 0, stream>>>(W1, W2, W3, m1, m2, m3, W1h, W2h, W3m, flags);

    gemm1_tall<<<1024, 512, 0, stream>>>(x, W1h, h1);
    gemm2_fused<HID><<<512, 512, 0, stream>>>(h1, W2h, W3m, Pp);
    k_final<<<1024, 256, 0, stream>>>(Pp, out);
}

// Round 15
// 357.258 us; speedup vs baseline: 2.7582x; 2.7582x over previous
//
#include <hip/hip_runtime.h>
#include <hip/hip_fp16.h>
#include <math.h>

typedef _Float16 half_t;
typedef __attribute__((ext_vector_type(8))) _Float16 f16x8;  // MFMA A/B frag
typedef __attribute__((ext_vector_type(4))) float   f32x4;   // MFMA C/D frag
typedef __attribute__((ext_vector_type(4))) float   float4v;

#define IN_F   1536
#define HID    640
#define OUT_F  10
#define NBATCH 65536

#define SB() __builtin_amdgcn_sched_barrier(0)

// ---------- helpers ----------

__device__ __forceinline__ void gll16(const void* g, const void* l) {
    __builtin_amdgcn_global_load_lds(
        (const __attribute__((address_space(1))) unsigned*)g,
        (__attribute__((address_space(3))) unsigned*)l, 16, 0, 0);
}

// exact-GELU via A&S 7.1.26 erf poly (|eps|<=1.5e-7, noise vs f16 rounding)
__device__ __forceinline__ float gelu_fast(float z) {
    float x  = 0.70710678118654752f * z;
    float ax = fabsf(x);
    float t  = 1.0f / (1.0f + 0.3275911f * ax);
    float p  = t * (0.254829592f +
               t * (-0.284496736f +
               t * (1.421413741f +
               t * (-1.453152027f +
               t * 1.061405429f))));
    float e  = __expf(-ax * ax);
    float er = 1.0f - p * e;
    er = (x < 0.0f) ? -er : er;
    return 0.5f * z * (1.0f + er);
}

// ---------- prep ----------

__global__ void k_detect(const unsigned* __restrict__ m, int nDwords, int* flags) {
    int f = 0, g = 0;
    for (int i = blockIdx.x * blockDim.x + threadIdx.x; i < nDwords;
         i += gridDim.x * blockDim.x) {
        unsigned d = m[i];
        f |= (d == 0x3F800000u);
        g |= (d != 0u) & (d != 1u) & (d != 0x3F800000u);
    }
    if (f) atomicOr(&flags[0], 1);
    if (g) atomicOr(&flags[1], 1);
}

__device__ __forceinline__ bool mask_at(const void* mask, int i, int isB, int isF) {
    if (isB) return ((const unsigned char*)mask)[i] != 0;
    if (isF) return ((const float*)mask)[i] != 0.0f;
    return ((const int*)mask)[i] != 0;
}

__global__ void k_mask_all(const float* __restrict__ W1, const float* __restrict__ W2,
                           const float* __restrict__ W3,
                           const void* __restrict__ m1, const void* __restrict__ m2,
                           const void* __restrict__ m3,
                           half_t* __restrict__ W1h, half_t* __restrict__ W2h,
                           float* __restrict__ W3m, const int* __restrict__ flags) {
    const int isB = flags[1], isF = flags[0];
    const int N1 = HID * IN_F, N2 = HID * HID, N3 = OUT_F * HID;
    const int NT = N1 + N2 + N3;
    for (int i = blockIdx.x * blockDim.x + threadIdx.x; i < NT;
         i += gridDim.x * blockDim.x) {
        if (i < N1) {
            W1h[i] = mask_at(m1, i, isB, isF) ? (half_t)W1[i] : (half_t)0.0f;
        } else if (i < N1 + N2) {
            int j = i - N1;
            W2h[j] = mask_at(m2, j, isB, isF) ? (half_t)W2[j] : (half_t)0.0f;
        } else {
            int j = i - N1 - N2;
            W3m[j] = mask_at(m3, j, isB, isF) ? W3[j] : 0.0f;
        }
    }
}

// ---------- GEMM1: 128x160 tile, 256 thr, 3 blocks/CU, depth-2 ring ----------
// h1[m][n] = gelu( sum_k x[m][k] * W1[n][k] ), f16 out.
// 4 waves (2m x 2n of 64x80), acc[4][5]=80; unified budget 80+~85 <= 170
// (LB(256,3)). LDS 2 x (A f32 16KB + B 10KB) = 52KB -> 3 blocks/CU (156KB).
// VMEM service ~10 B/cyc PER BLOCK (R6/R9/R11/m97 fit) -> 3 blocks = lever.
// Two-barrier counted-vmcnt ring (R9-proven): entry vmcnt(cls) retires L(ks)
// keeping L(ks+1); READY; ds_read frags; lgkm(0); SB; cvt; CONSUMED;
// STAGE(ks+2)->slab ks%2; MFMA. Ops/tile: waves 0-1: 4A+3B=7; waves 2-3: 4A+2B=6.
// Layouts (measured conflict-free): A f32 [128][128B] 8-slot XOR;
// B pair-packed [80][128B]. gll dests linear, sources inverse-swizzled.
__global__ __launch_bounds__(256, 3) void gemm1_tall(
    const float* __restrict__ Ain, const half_t* __restrict__ Bw,
    half_t* __restrict__ Cout) {
    constexpr int K    = IN_F;
    constexpr int NK   = K / 32;                     // 48
    constexpr int SLAB = 16384 + 10240;              // 26KB
    __shared__ __align__(16) char lds[2 * SLAB];     // 52KB

    const int t = threadIdx.x, lane = t & 63, wid = t >> 6;
    const int wr = wid >> 1, wc = wid & 1;

    // XCD-bijective swizzle; nwg = 2048 = 8*256, n-fastest (4 blocks/panel).
    const int q       = (int)gridDim.x >> 3;
    const int logical = ((int)blockIdx.x & 7) * q + ((int)blockIdx.x >> 3);
    const int mb = logical >> 2, nbk = logical & 3;
    const long mBase = (long)mb * 128;
    const int  n0    = nbk * 160;

    const int rr = lane & 15, k8 = lane >> 4;

    // fragment read bases
    int aRd[4], bRd[5];
    {
#pragma unroll
        for (int mf = 0; mf < 4; ++mf) {
            const int row = wr * 64 + mf * 16 + rr;
            aRd[mf] = row * 128 + (((2 * k8) ^ (row & 7)) << 4);
        }
#pragma unroll
        for (int nf = 0; nf < 5; ++nf) {
            const int nrow = wc * 80 + nf * 16 + rr, ln = nrow >> 1;
            bRd[nf] = 16384 + ln * 128 +
                      ((((((nrow & 1) << 2) | k8)) ^ (ln & 7)) << 4);
        }
    }

    // staging sources (inverse-swizzled), linear gll dests
    // A: 4 ops, o=(t+r*256)*16 -> row=(t>>3)+32r, slot=t&7 (256%8==0),
    //    kq=slot^(row&7) (32r&7==0 -> invariant)
    const float* srcAf;
    {
        const int row = t >> 3, kq = (t & 7) ^ ((t >> 3) & 7);
        srcAf = Ain + (mBase + row) * (long)K + kq * 4;
    }
    // B: 2 ops all thr + 3rd for t<128; line=(t>>3)+32r, orig=(t&7)^(line&7)
    //    (invariant), nrow=2*line+(orig>>2) = base+64r, kq=orig&3
    const half_t* srcB;
    {
        const int line = t >> 3, orig = (t & 7) ^ (line & 7);
        const int nrow = 2 * line + (orig >> 2), kq = orig & 3;
        srcB = Bw + (size_t)(n0 + nrow) * K + kq * 8;
    }

    auto STAGE = [&](int k, int sb) {
        const size_t ko = (size_t)k * 32;
#pragma unroll
        for (int r = 0; r < 4; ++r)
            gll16(srcAf + ko + (size_t)r * 32 * K,
                  &lds[sb + (t + r * 256) * 16]);
#pragma unroll
        for (int r = 0; r < 2; ++r)
            gll16(srcB + ko + (size_t)r * 64 * K,
                  &lds[sb + 16384 + (t + r * 256) * 16]);
        if (t < 128)
            gll16(srcB + ko + (size_t)128 * K,
                  &lds[sb + 16384 + (t + 512) * 16]);
    };

    f32x4 acc[4][5];
#pragma unroll
    for (int mf = 0; mf < 4; ++mf)
#pragma unroll
        for (int nf = 0; nf < 5; ++nf) {
            f32x4 z = {0.f, 0.f, 0.f, 0.f};
            acc[mf][nf] = z;
        }

    STAGE(0, 0); SB();
    STAGE(1, SLAB); SB();

    for (int ks = 0; ks < NK; ++ks) {
        const int cb = (ks & 1) * SLAB;
        if (ks + 1 < NK) {
            if (wid < 2) asm volatile("s_waitcnt vmcnt(7)" ::: "memory");
            else         asm volatile("s_waitcnt vmcnt(6)" ::: "memory");
        } else {
            asm volatile("s_waitcnt vmcnt(0)" ::: "memory");
        }
        __builtin_amdgcn_s_barrier();                 // READY(ks)
        f16x8 bv[5];
#pragma unroll
        for (int nf = 0; nf < 5; ++nf)
            bv[nf] = *(const f16x8*)(&lds[cb + bRd[nf]]);
        f16x8 av[4];
#pragma unroll
        for (int mf = 0; mf < 4; ++mf) {
            float4v alo = *(const float4v*)(&lds[cb + aRd[mf]]);
            float4v ahi = *(const float4v*)(&lds[cb + (aRd[mf] ^ 16)]);
            f16x8 h;
#pragma unroll
            for (int i = 0; i < 4; ++i) {
                h[i]     = (half_t)alo[i];
                h[i + 4] = (half_t)ahi[i];
            }
            av[mf] = h;
        }
        asm volatile("s_waitcnt lgkmcnt(0)" ::: "memory");
        SB();                                          // rule 18
        __builtin_amdgcn_s_barrier();                  // CONSUMED(ks)
        if (ks + 2 < NK) { STAGE(ks + 2, cb); SB(); }
#pragma unroll
        for (int mf = 0; mf < 4; ++mf)
#pragma unroll
            for (int nf = 0; nf < 5; ++nf)
                acc[mf][nf] = __builtin_amdgcn_mfma_f32_16x16x32_f16(
                    av[mf], bv[nf], acc[mf][nf], 0, 0, 0);
    }

    // epilogue: C/D frag col=lane&15, row=(lane>>4)*4+j
    const int crow0 = (lane >> 4) * 4;
    const int ccol  = lane & 15;
#pragma unroll
    for (int mf = 0; mf < 4; ++mf)
#pragma unroll
        for (int nf = 0; nf < 5; ++nf)
#pragma unroll
            for (int j = 0; j < 4; ++j) {
                const long row = mBase + wr * 64 + mf * 16 + crow0 + j;
                const int  col = n0 + wc * 80 + nf * 16 + ccol;
                Cout[row * HID + col] = (half_t)gelu_fast(acc[mf][nf][j]);
            }
}

// ---------- GEMM2 (+ fused layer 3), R13-proven, unchanged ----------
template <int K>
__global__ __launch_bounds__(512, 2) void gemm2_fused(
    const half_t* __restrict__ Ain, const half_t* __restrict__ Bw,
    const float* __restrict__ W3, float* __restrict__ Pout) {
    constexpr int NK     = K / 32;                    // 20
    constexpr int ABYTES = 16384;
    constexpr int SLAB   = ABYTES + 20480;
    __shared__ __align__(16) char lds[3 * SLAB];      // 108KB

    const int t = threadIdx.x, lane = t & 63, wid = t >> 6;
    const int wr = wid >> 2, wc = wid & 3;

    const int q       = (int)gridDim.x >> 3;
    const int logical = ((int)blockIdx.x & 7) * q + ((int)blockIdx.x >> 3);
    const int mb = logical >> 1, nbk = logical & 1;
    const long mBase = (long)mb * 256;
    const int  n0    = nbk * 320;

    const int rr = lane & 15, k8 = lane >> 4;

    int aBase0 = 0, bBase = 0;
    {
        const int row = wr * 128 + rr, ln = row >> 1;
        aBase0 = ln * 128 + ((((((row & 1) << 2) | k8)) ^ (ln & 7)) << 4);
        const int nrow = wc * 80 + rr, lnb = nrow >> 1;
        bBase = ABYTES + lnb * 128 +
                ((((((nrow & 1) << 2) | k8)) ^ (lnb & 7)) << 4);
    }

    const half_t* srcAh;
    {
        const int line = t >> 3, orig = (t & 7) ^ (line & 7);
        const int row = 2 * line + (orig >> 2), kq = orig & 3;
        srcAh = Ain + (mBase + row) * (long)K + kq * 8;
    }
    const half_t* srcB;
    {
        const int line = t >> 3, orig = (t & 7) ^ (line & 7);
        const int nrow = 2 * line + (orig >> 2), kq = orig & 3;
        srcB = Bw + (size_t)(n0 + nrow) * K + kq * 8;
    }

    auto STAGE = [&](int k, int sb) {
        const size_t ko = (size_t)k * 32;
#pragma unroll
        for (int r = 0; r < 2; ++r)
            gll16(srcAh + ko + (size_t)r * 128 * K,
                  &lds[sb + (t + r * 512) * 16]);
#pragma unroll
        for (int r = 0; r < 2; ++r)
            gll16(srcB + ko + (size_t)r * 128 * K,
                  &lds[sb + ABYTES + (t + r * 512) * 16]);
        if (t < 256)
            gll16(srcB + ko + (size_t)2 * 128 * K,
                  &lds[sb + ABYTES + (t + 1024) * 16]);
    };

    f32x4 acc[8][5];
#pragma unroll
    for (int mf = 0; mf < 8; ++mf)
#pragma unroll
        for (int nf = 0; nf < 5; ++nf) {
            f32x4 z = {0.f, 0.f, 0.f, 0.f};
            acc[mf][nf] = z;
        }

    STAGE(0, 0); SB();
    STAGE(1, SLAB); SB();

    for (int ks = 0; ks < NK; ++ks) {
        if (ks + 1 < NK) {
            if (wid < 4) asm volatile("s_waitcnt vmcnt(5)" ::: "memory");
            else         asm volatile("s_waitcnt vmcnt(4)" ::: "memory");
        } else {
            asm volatile("s_waitcnt vmcnt(0)" ::: "memory");
        }
        __builtin_amdgcn_s_barrier();
        const int cb = (ks % 3) * SLAB;
        if (ks + 2 < NK) { STAGE(ks + 2, ((ks + 2) % 3) * SLAB); SB(); }

        f16x8 bv[5];
#pragma unroll
        for (int nf = 0; nf < 5; ++nf)
            bv[nf] = *(const f16x8*)(&lds[cb + bBase + nf * 1024]);
        f16x8 av[8];
#pragma unroll
        for (int mf = 0; mf < 8; ++mf)
            av[mf] = *(const f16x8*)(&lds[cb + aBase0 + mf * 1024]);
#pragma unroll
        for (int mf = 0; mf < 8; ++mf)
#pragma unroll
            for (int nf = 0; nf < 5; ++nf)
                acc[mf][nf] = __builtin_amdgcn_mfma_f32_16x16x32_f16(
                    av[mf], bv[nf], acc[mf][nf], 0, 0, 0);
    }

    // fused layer 3 epilogue (R13-proven)
    const int crow0 = (lane >> 4) * 4;
    const int ccol  = lane & 15;
    float w3[OUT_F][5];
#pragma unroll
    for (int o = 0; o < OUT_F; ++o)
#pragma unroll
        for (int nf = 0; nf < 5; ++nf)
            w3[o][nf] = W3[o * HID + n0 + wc * 80 + nf * 16 + ccol];
    float* slice = Pout + (size_t)(nbk * 4 + wc) * NBATCH * OUT_F;
#pragma unroll
    for (int mf = 0; mf < 8; ++mf)
#pragma unroll
        for (int j = 0; j < 4; ++j) {
            float p[OUT_F];
#pragma unroll
            for (int o = 0; o < OUT_F; ++o) p[o] = 0.f;
#pragma unroll
            for (int nf = 0; nf < 5; ++nf) {
                const float v = gelu_fast(acc[mf][nf][j]);
#pragma unroll
                for (int o = 0; o < OUT_F; ++o) p[o] += v * w3[o][nf];
            }
#pragma unroll
            for (int mask = 1; mask < 16; mask <<= 1)
#pragma unroll
                for (int o = 0; o < OUT_F; ++o)
                    p[o] += __shfl_xor(p[o], mask);
            float v = 0.f;
#pragma unroll
            for (int o = 0; o < OUT_F; ++o) v = (ccol == o) ? p[o] : v;
            const long row = mBase + wr * 128 + mf * 16 + crow0 + j;
            if (ccol < OUT_F) slice[row * OUT_F + ccol] = v;
        }
}

// ---------- final: out = sum of 8 partial slices ----------
__global__ void k_final(const float* __restrict__ P, float* __restrict__ out) {
    const int n = NBATCH * OUT_F;
    for (int i = blockIdx.x * blockDim.x + threadIdx.x; i < n;
         i += gridDim.x * blockDim.x) {
        float s0 = P[i]                 + P[(size_t)1 * n + i];
        float s1 = P[(size_t)2 * n + i] + P[(size_t)3 * n + i];
        float s2 = P[(size_t)4 * n + i] + P[(size_t)5 * n + i];
        float s3 = P[(size_t)6 * n + i] + P[(size_t)7 * n + i];
        out[i] = (s0 + s1) + (s2 + s3);
    }
}

// ---------- launch ----------

extern "C" void kernel_launch(void* const* d_in, const int* in_sizes, int n_in,
                              void* d_out, int out_size, void* d_ws, size_t ws_size,
                              hipStream_t stream) {
    const float* x  = (const float*)d_in[0];
    const float* W1 = (const float*)d_in[1];
    const float* W2 = (const float*)d_in[2];
    const float* W3 = (const float*)d_in[3];
    const void*  m1 = d_in[4];
    const void*  m2 = d_in[5];
    const void*  m3 = d_in[6];
    float* out = (float*)d_out;

    char* ws = (char*)d_ws;
    int*    flags = (int*)ws;
    half_t* W1h = (half_t*)(ws + 256);                      // 640*1536*2
    half_t* W2h = (half_t*)(ws + 256 + 1966080);            // 640*640*2
    float*  W3m = (float*)(ws + 256 + 1966080 + 819200);    // 25600
    half_t* h1  = (half_t*)(ws + 256 + 1966080 + 819200 + 25600);
    float*  Pp  = (float*)((char*)h1 + (size_t)NBATCH * HID * 2);  // 8*655360*4

    hipMemsetAsync(flags, 0, 8, stream);
    k_detect<<<64, 256, 0, stream>>>((const unsigned*)m1, 65536, flags);
    k_mask_all<<<1024, 256, 0, stream>>>(W1, W2, W3, m1, m2, m3, W1h, W2h, W3m, flags);

    gemm1_tall<<<2048, 256, 0, stream>>>(x, W1h, h1);
    gemm2_fused<HID><<<512, 512, 0, stream>>>(h1, W2h, W3m, Pp);
    k_final<<<1024, 256, 0, stream>>>(Pp, out);
}

// Round 16
// 325.966 us; speedup vs baseline: 3.0230x; 1.0960x over previous
//
#include <hip/hip_runtime.h>
#include <hip/hip_fp16.h>
#include <math.h>

typedef _Float16 half_t;
typedef __attribute__((ext_vector_type(8))) _Float16 f16x8;  // MFMA A/B frag
typedef __attribute__((ext_vector_type(4))) float   f32x4;   // MFMA C/D frag
typedef __attribute__((ext_vector_type(4))) float   float4v;

#define IN_F   1536
#define HID    640
#define OUT_F  10
#define NBATCH 65536

#define SB() __builtin_amdgcn_sched_barrier(0)

// ---------- helpers ----------

__device__ __forceinline__ void gll16(const void* g, const void* l) {
    __builtin_amdgcn_global_load_lds(
        (const __attribute__((address_space(1))) unsigned*)g,
        (__attribute__((address_space(3))) unsigned*)l, 16, 0, 0);
}

// exact-GELU via A&S 7.1.26 erf poly (|eps|<=1.5e-7, noise vs f16 rounding)
__device__ __forceinline__ float gelu_fast(float z) {
    float x  = 0.70710678118654752f * z;
    float ax = fabsf(x);
    float t  = 1.0f / (1.0f + 0.3275911f * ax);
    float p  = t * (0.254829592f +
               t * (-0.284496736f +
               t * (1.421413741f +
               t * (-1.453152027f +
               t * 1.061405429f))));
    float e  = __expf(-ax * ax);
    float er = 1.0f - p * e;
    er = (x < 0.0f) ? -er : er;
    return 0.5f * z * (1.0f + er);
}

// ---------- prep ----------

__global__ void k_detect(const unsigned* __restrict__ m, int nDwords, int* flags) {
    int f = 0, g = 0;
    for (int i = blockIdx.x * blockDim.x + threadIdx.x; i < nDwords;
         i += gridDim.x * blockDim.x) {
        unsigned d = m[i];
        f |= (d == 0x3F800000u);
        g |= (d != 0u) & (d != 1u) & (d != 0x3F800000u);
    }
    if (f) atomicOr(&flags[0], 1);
    if (g) atomicOr(&flags[1], 1);
}

__device__ __forceinline__ bool mask_at(const void* mask, int i, int isB, int isF) {
    if (isB) return ((const unsigned char*)mask)[i] != 0;
    if (isF) return ((const float*)mask)[i] != 0.0f;
    return ((const int*)mask)[i] != 0;
}

__global__ void k_mask_all(const float* __restrict__ W1, const float* __restrict__ W2,
                           const float* __restrict__ W3,
                           const void* __restrict__ m1, const void* __restrict__ m2,
                           const void* __restrict__ m3,
                           half_t* __restrict__ W1h, half_t* __restrict__ W2h,
                           float* __restrict__ W3m, const int* __restrict__ flags) {
    const int isB = flags[1], isF = flags[0];
    const int N1 = HID * IN_F, N2 = HID * HID, N3 = OUT_F * HID;
    const int NT = N1 + N2 + N3;
    for (int i = blockIdx.x * blockDim.x + threadIdx.x; i < NT;
         i += gridDim.x * blockDim.x) {
        if (i < N1) {
            W1h[i] = mask_at(m1, i, isB, isF) ? (half_t)W1[i] : (half_t)0.0f;
        } else if (i < N1 + N2) {
            int j = i - N1;
            W2h[j] = mask_at(m2, j, isB, isF) ? (half_t)W2[j] : (half_t)0.0f;
        } else {
            int j = i - N1 - N2;
            W3m[j] = mask_at(m3, j, isB, isF) ? W3[j] : 0.0f;
        }
    }
}

// ---------- GEMM1: 128x320 tile, 256 thr, 2 blocks/CU, depth-2 ring ----------
// h1[m][n] = gelu( sum_k x[m][k] * W1[n][k] ), f16 out.
// 4 waves (2m x 2n of 64x160), acc[4][10]=160 (AGPR); 256 thr, 2 blocks/CU =
// 8 waves/CU = 2 waves/SIMD — R11's proven ~270-unified-reg budget.
// Service model: ~4.5-6 TB/s PER resident block, additive (R13/R6/R15 fit) ->
// 2 blocks x min staged bytes (1.81 GB) is the sweep optimum.
// LDS: 2 slabs x (A f32 16KB + B 20KB) = 72KB -> 2 blocks (144KB).
// Uniform 9 gll ops/thread (A 4 + B 5), entry vmcnt(9) retires L(ks) keeping
// L(ks+1). Two-barrier ring (R15-proven): READY; ds_read; lgkm(0); SB;
// CONSUMED; STAGE(ks+2)->slab ks%2; MFMA.
// Layouts (measured conflict-free): A f32 [128][128B] 8-slot XOR;
// B pair-packed [160 lines][128B]. gll dests linear, sources inverse-swizzled.
__global__ __launch_bounds__(256, 2) void gemm1_tall(
    const float* __restrict__ Ain, const half_t* __restrict__ Bw,
    half_t* __restrict__ Cout) {
    constexpr int K    = IN_F;
    constexpr int NK   = K / 32;                     // 48
    constexpr int SLAB = 16384 + 20480;              // A 16KB + B 20KB
    __shared__ __align__(16) char lds[2 * SLAB];     // 72KB

    const int t = threadIdx.x, lane = t & 63, wid = t >> 6;
    const int wr = wid >> 1, wc = wid & 1;

    // XCD-bijective swizzle; nwg = 1024 = 8*128, n-fastest (2 blocks/panel).
    const int q       = (int)gridDim.x >> 3;
    const int logical = ((int)blockIdx.x & 7) * q + ((int)blockIdx.x >> 3);
    const int mb = logical >> 1, nbk = logical & 1;
    const long mBase = (long)mb * 128;
    const int  n0    = nbk * 320;

    const int rr = lane & 15, k8 = lane >> 4;

    // fragment read bases
    int aRd[4], bRd[10];
    {
#pragma unroll
        for (int mf = 0; mf < 4; ++mf) {
            const int row = wr * 64 + mf * 16 + rr;
            aRd[mf] = row * 128 + (((2 * k8) ^ (row & 7)) << 4);
        }
#pragma unroll
        for (int nf = 0; nf < 10; ++nf) {
            const int nrow = wc * 160 + nf * 16 + rr, ln = nrow >> 1;
            bRd[nf] = 16384 + ln * 128 +
                      ((((((nrow & 1) << 2) | k8)) ^ (ln & 7)) << 4);
        }
    }

    // staging sources (inverse-swizzled), linear gll dests
    // A: 4 ops, o=(t+r*256)*16 -> row=(t>>3)+32r, slot=t&7, kq=slot^(row&7)
    //    (32r&7==0 -> kq invariant in r)
    const float* srcAf;
    {
        const int row = t >> 3, kq = (t & 7) ^ ((t >> 3) & 7);
        srcAf = Ain + (mBase + row) * (long)K + kq * 4;
    }
    // B: 5 ops, o=(t+r*256)*16 -> line=(t>>3)+32r, slot=t&7, orig=slot^(line&7)
    //    (invariant), nrow=2*line+(orig>>2) = base+64r, kq=orig&3
    const half_t* srcB;
    {
        const int line = t >> 3, orig = (t & 7) ^ (line & 7);
        const int nrow = 2 * line + (orig >> 2), kq = orig & 3;
        srcB = Bw + (size_t)(n0 + nrow) * K + kq * 8;
    }

    auto STAGE = [&](int k, int sb) {
        const size_t ko = (size_t)k * 32;
#pragma unroll
        for (int r = 0; r < 4; ++r)
            gll16(srcAf + ko + (size_t)r * 32 * K,
                  &lds[sb + (t + r * 256) * 16]);
#pragma unroll
        for (int r = 0; r < 5; ++r)
            gll16(srcB + ko + (size_t)r * 64 * K,
                  &lds[sb + 16384 + (t + r * 256) * 16]);
    };

    f32x4 acc[4][10];
#pragma unroll
    for (int mf = 0; mf < 4; ++mf)
#pragma unroll
        for (int nf = 0; nf < 10; ++nf) {
            f32x4 z = {0.f, 0.f, 0.f, 0.f};
            acc[mf][nf] = z;
        }

    STAGE(0, 0); SB();
    STAGE(1, SLAB); SB();

    for (int ks = 0; ks < NK; ++ks) {
        const int cb = (ks & 1) * SLAB;
        if (ks + 1 < NK) asm volatile("s_waitcnt vmcnt(9)" ::: "memory");
        else             asm volatile("s_waitcnt vmcnt(0)" ::: "memory");
        __builtin_amdgcn_s_barrier();                 // READY(ks)
        f16x8 bv[10];
#pragma unroll
        for (int nf = 0; nf < 10; ++nf)
            bv[nf] = *(const f16x8*)(&lds[cb + bRd[nf]]);
        f16x8 av[4];
#pragma unroll
        for (int mf = 0; mf < 4; ++mf) {
            float4v alo = *(const float4v*)(&lds[cb + aRd[mf]]);
            float4v ahi = *(const float4v*)(&lds[cb + (aRd[mf] ^ 16)]);
            f16x8 h;
#pragma unroll
            for (int i = 0; i < 4; ++i) {
                h[i]     = (half_t)alo[i];
                h[i + 4] = (half_t)ahi[i];
            }
            av[mf] = h;
        }
        asm volatile("s_waitcnt lgkmcnt(0)" ::: "memory");
        SB();                                          // rule 18
        __builtin_amdgcn_s_barrier();                  // CONSUMED(ks)
        if (ks + 2 < NK) { STAGE(ks + 2, cb); SB(); }
#pragma unroll
        for (int mf = 0; mf < 4; ++mf)
#pragma unroll
            for (int nf = 0; nf < 10; ++nf)
                acc[mf][nf] = __builtin_amdgcn_mfma_f32_16x16x32_f16(
                    av[mf], bv[nf], acc[mf][nf], 0, 0, 0);
    }

    // epilogue: C/D frag col=lane&15, row=(lane>>4)*4+j
    const int crow0 = (lane >> 4) * 4;
    const int ccol  = lane & 15;
#pragma unroll
    for (int mf = 0; mf < 4; ++mf)
#pragma unroll
        for (int nf = 0; nf < 10; ++nf)
#pragma unroll
            for (int j = 0; j < 4; ++j) {
                const long row = mBase + wr * 64 + mf * 16 + crow0 + j;
                const int  col = n0 + wc * 160 + nf * 16 + ccol;
                Cout[row * HID + col] = (half_t)gelu_fast(acc[mf][nf][j]);
            }
}

// ---------- GEMM2 (+ fused layer 3), R13-proven, unchanged ----------
template <int K>
__global__ __launch_bounds__(512, 2) void gemm2_fused(
    const half_t* __restrict__ Ain, const half_t* __restrict__ Bw,
    const float* __restrict__ W3, float* __restrict__ Pout) {
    constexpr int NK     = K / 32;                    // 20
    constexpr int ABYTES = 16384;
    constexpr int SLAB   = ABYTES + 20480;
    __shared__ __align__(16) char lds[3 * SLAB];      // 108KB

    const int t = threadIdx.x, lane = t & 63, wid = t >> 6;
    const int wr = wid >> 2, wc = wid & 3;

    const int q       = (int)gridDim.x >> 3;
    const int logical = ((int)blockIdx.x & 7) * q + ((int)blockIdx.x >> 3);
    const int mb = logical >> 1, nbk = logical & 1;
    const long mBase = (long)mb * 256;
    const int  n0    = nbk * 320;

    const int rr = lane & 15, k8 = lane >> 4;

    int aBase0 = 0, bBase = 0;
    {
        const int row = wr * 128 + rr, ln = row >> 1;
        aBase0 = ln * 128 + ((((((row & 1) << 2) | k8)) ^ (ln & 7)) << 4);
        const int nrow = wc * 80 + rr, lnb = nrow >> 1;
        bBase = ABYTES + lnb * 128 +
                ((((((nrow & 1) << 2) | k8)) ^ (lnb & 7)) << 4);
    }

    const half_t* srcAh;
    {
        const int line = t >> 3, orig = (t & 7) ^ (line & 7);
        const int row = 2 * line + (orig >> 2), kq = orig & 3;
        srcAh = Ain + (mBase + row) * (long)K + kq * 8;
    }
    const half_t* srcB;
    {
        const int line = t >> 3, orig = (t & 7) ^ (line & 7);
        const int nrow = 2 * line + (orig >> 2), kq = orig & 3;
        srcB = Bw + (size_t)(n0 + nrow) * K + kq * 8;
    }

    auto STAGE = [&](int k, int sb) {
        const size_t ko = (size_t)k * 32;
#pragma unroll
        for (int r = 0; r < 2; ++r)
            gll16(srcAh + ko + (size_t)r * 128 * K,
                  &lds[sb + (t + r * 512) * 16]);
#pragma unroll
        for (int r = 0; r < 2; ++r)
            gll16(srcB + ko + (size_t)r * 128 * K,
                  &lds[sb + ABYTES + (t + r * 512) * 16]);
        if (t < 256)
            gll16(srcB + ko + (size_t)2 * 128 * K,
                  &lds[sb + ABYTES + (t + 1024) * 16]);
    };

    f32x4 acc[8][5];
#pragma unroll
    for (int mf = 0; mf < 8; ++mf)
#pragma unroll
        for (int nf = 0; nf < 5; ++nf) {
            f32x4 z = {0.f, 0.f, 0.f, 0.f};
            acc[mf][nf] = z;
        }

    STAGE(0, 0); SB();
    STAGE(1, SLAB); SB();

    for (int ks = 0; ks < NK; ++ks) {
        if (ks + 1 < NK) {
            if (wid < 4) asm volatile("s_waitcnt vmcnt(5)" ::: "memory");
            else         asm volatile("s_waitcnt vmcnt(4)" ::: "memory");
        } else {
            asm volatile("s_waitcnt vmcnt(0)" ::: "memory");
        }
        __builtin_amdgcn_s_barrier();
        const int cb = (ks % 3) * SLAB;
        if (ks + 2 < NK) { STAGE(ks + 2, ((ks + 2) % 3) * SLAB); SB(); }

        f16x8 bv[5];
#pragma unroll
        for (int nf = 0; nf < 5; ++nf)
            bv[nf] = *(const f16x8*)(&lds[cb + bBase + nf * 1024]);
        f16x8 av[8];
#pragma unroll
        for (int mf = 0; mf < 8; ++mf)
            av[mf] = *(const f16x8*)(&lds[cb + aBase0 + mf * 1024]);
#pragma unroll
        for (int mf = 0; mf < 8; ++mf)
#pragma unroll
            for (int nf = 0; nf < 5; ++nf)
                acc[mf][nf] = __builtin_amdgcn_mfma_f32_16x16x32_f16(
                    av[mf], bv[nf], acc[mf][nf], 0, 0, 0);
    }

    // fused layer 3 epilogue (R13-proven)
    const int crow0 = (lane >> 4) * 4;
    const int ccol  = lane & 15;
    float w3[OUT_F][5];
#pragma unroll
    for (int o = 0; o < OUT_F; ++o)
#pragma unroll
        for (int nf = 0; nf < 5; ++nf)
            w3[o][nf] = W3[o * HID + n0 + wc * 80 + nf * 16 + ccol];
    float* slice = Pout + (size_t)(nbk * 4 + wc) * NBATCH * OUT_F;
#pragma unroll
    for (int mf = 0; mf < 8; ++mf)
#pragma unroll
        for (int j = 0; j < 4; ++j) {
            float p[OUT_F];
#pragma unroll
            for (int o = 0; o < OUT_F; ++o) p[o] = 0.f;
#pragma unroll
            for (int nf = 0; nf < 5; ++nf) {
                const float v = gelu_fast(acc[mf][nf][j]);
#pragma unroll
                for (int o = 0; o < OUT_F; ++o) p[o] += v * w3[o][nf];
            }
#pragma unroll
            for (int mask = 1; mask < 16; mask <<= 1)
#pragma unroll
                for (int o = 0; o < OUT_F; ++o)
                    p[o] += __shfl_xor(p[o], mask);
            float v = 0.f;
#pragma unroll
            for (int o = 0; o < OUT_F; ++o) v = (ccol == o) ? p[o] : v;
            const long row = mBase + wr * 128 + mf * 16 + crow0 + j;
            if (ccol < OUT_F) slice[row * OUT_F + ccol] = v;
        }
}

// ---------- final: out = sum of 8 partial slices ----------
__global__ void k_final(const float* __restrict__ P, float* __restrict__ out) {
    const int n = NBATCH * OUT_F;
    for (int i = blockIdx.x * blockDim.x + threadIdx.x; i < n;
         i += gridDim.x * blockDim.x) {
        float s0 = P[i]                 + P[(size_t)1 * n + i];
        float s1 = P[(size_t)2 * n + i] + P[(size_t)3 * n + i];
        float s2 = P[(size_t)4 * n + i] + P[(size_t)5 * n + i];
        float s3 = P[(size_t)6 * n + i] + P[(size_t)7 * n + i];
        out[i] = (s0 + s1) + (s2 + s3);
    }
}

// ---------- launch ----------

extern "C" void kernel_launch(void* const* d_in, const int* in_sizes, int n_in,
                              void* d_out, int out_size, void* d_ws, size_t ws_size,
                              hipStream_t stream) {
    const float* x  = (const float*)d_in[0];
    const float* W1 = (const float*)d_in[1];
    const float* W2 = (const float*)d_in[2];
    const float* W3 = (const float*)d_in[3];
    const void*  m1 = d_in[4];
    const void*  m2 = d_in[5];
    const void*  m3 = d_in[6];
    float* out = (float*)d_out;

    char* ws = (char*)d_ws;
    int*    flags = (int*)ws;
    half_t* W1h = (half_t*)(ws + 256);                      // 640*1536*2
    half_t* W2h = (half_t*)(ws + 256 + 1966080);            // 640*640*2
    float*  W3m = (float*)(ws + 256 + 1966080 + 819200);    // 25600
    half_t* h1  = (half_t*)(ws + 256 + 1966080 + 819200 + 25600);
    float*  Pp  = (float*)((char*)h1 + (size_t)NBATCH * HID * 2);  // 8*655360*4

    hipMemsetAsync(flags, 0, 8, stream);
    k_detect<<<64, 256, 0, stream>>>((const unsigned*)m1, 65536, flags);
    k_mask_all<<<1024, 256, 0, stream>>>(W1, W2, W3, m1, m2, m3, W1h, W2h, W3m, flags);

    gemm1_tall<<<1024, 256, 0, stream>>>(x, W1h, h1);
    gemm2_fused<HID><<<512, 512, 0, stream>>>(h1, W2h, W3m, Pp);
    k_final<<<1024, 256, 0, stream>>>(Pp, out);
}

// Round 18
// 317.530 us; speedup vs baseline: 3.1033x; 1.0266x over previous
//
#include <hip/hip_runtime.h>
#include <hip/hip_fp16.h>
#include <math.h>

typedef _Float16 half_t;
typedef __attribute__((ext_vector_type(8))) _Float16 f16x8;  // MFMA A/B frag
typedef __attribute__((ext_vector_type(4))) float   f32x4;   // MFMA C/D frag
typedef __attribute__((ext_vector_type(4))) float   float4v;

#define IN_F   1536
#define HID    640
#define OUT_F  10
#define NBATCH 65536

#define SB() __builtin_amdgcn_sched_barrier(0)

// ---------- helpers ----------

__device__ __forceinline__ void gll16(const void* g, const void* l) {
    __builtin_amdgcn_global_load_lds(
        (const __attribute__((address_space(1))) unsigned*)g,
        (__attribute__((address_space(3))) unsigned*)l, 16, 0, 0);
}

// exact-GELU via A&S 7.1.26 erf poly (|eps|<=1.5e-7, noise vs f16 rounding)
__device__ __forceinline__ float gelu_fast(float z) {
    float x  = 0.70710678118654752f * z;
    float ax = fabsf(x);
    float t  = 1.0f / (1.0f + 0.3275911f * ax);
    float p  = t * (0.254829592f +
               t * (-0.284496736f +
               t * (1.421413741f +
               t * (-1.453152027f +
               t * 1.061405429f))));
    float e  = __expf(-ax * ax);
    float er = 1.0f - p * e;
    er = (x < 0.0f) ? -er : er;
    return 0.5f * z * (1.0f + er);
}

// ---------- prep ----------

__global__ void k_detect(const unsigned* __restrict__ m, int nDwords, int* flags) {
    int f = 0, g = 0;
    for (int i = blockIdx.x * blockDim.x + threadIdx.x; i < nDwords;
         i += gridDim.x * blockDim.x) {
        unsigned d = m[i];
        f |= (d == 0x3F800000u);
        g |= (d != 0u) & (d != 1u) & (d != 0x3F800000u);
    }
    if (f) atomicOr(&flags[0], 1);
    if (g) atomicOr(&flags[1], 1);
}

__device__ __forceinline__ bool mask_at(const void* mask, int i, int isB, int isF) {
    if (isB) return ((const unsigned char*)mask)[i] != 0;
    if (isF) return ((const float*)mask)[i] != 0.0f;
    return ((const int*)mask)[i] != 0;
}

__global__ void k_mask_all(const float* __restrict__ W1, const float* __restrict__ W2,
                           const float* __restrict__ W3,
                           const void* __restrict__ m1, const void* __restrict__ m2,
                           const void* __restrict__ m3,
                           half_t* __restrict__ W1h, half_t* __restrict__ W2h,
                           float* __restrict__ W3m, const int* __restrict__ flags) {
    const int isB = flags[1], isF = flags[0];
    const int N1 = HID * IN_F, N2 = HID * HID, N3 = OUT_F * HID;
    const int NT = N1 + N2 + N3;
    for (int i = blockIdx.x * blockDim.x + threadIdx.x; i < NT;
         i += gridDim.x * blockDim.x) {
        if (i < N1) {
            W1h[i] = mask_at(m1, i, isB, isF) ? (half_t)W1[i] : (half_t)0.0f;
        } else if (i < N1 + N2) {
            int j = i - N1;
            W2h[j] = mask_at(m2, j, isB, isF) ? (half_t)W2[j] : (half_t)0.0f;
        } else {
            int j = i - N1 - N2;
            W3m[j] = mask_at(m3, j, isB, isF) ? W3[j] : 0.0f;
        }
    }
}

// ---------- GEMM1: R11 ring, fine-interleaved compute (race-fixed) ----------
// h1[m][n] = gelu( sum_k x[m][k] * W1[n][k] ), f16 out.
// BM=256, BN=320, BK=32. 512 thr = 8 waves (2m x 4n), per-wave C = 128x80,
// acc[8][5]=160. LDS 3-slab ring 156KB. R11's proven protocol: entry
// vmcnt(7/6) retires own L(ks); ONE s_barrier (READY: slab ks fully staged by
// ALL waves; also all reads of slab ks-1 done -> STAGE(ks+2) into it safe).
// NEW vs R11 (the only delta): after the barrier the step runs as 2 phases,
// each {ds_read half; issue partial STAGE(ks+2); lgkm0; SB; cvt; setprio(1);
// 20 MFMA; setprio(0)} — staging issue interleaved between MFMA clusters
// (m201's lever), monotone issue order so vmcnt counts are unchanged.
// R17's bug (ds_read BEFORE the READY barrier = race on other waves' gll
// writes) is fixed: all reads of slab ks occur after the barrier.
__global__ __launch_bounds__(512, 2) void gemm1_tall(
    const float* __restrict__ Ain, const half_t* __restrict__ Bw,
    half_t* __restrict__ Cout) {
    constexpr int K    = IN_F;
    constexpr int NK   = K / 32;                     // 48
    constexpr int SLAB = 32768 + 20480;              // A f32 32KB + B 20KB
    __shared__ __align__(16) char lds[3 * SLAB];     // 156KB

    const int t = threadIdx.x, lane = t & 63, wid = t >> 6;
    const int wr = wid >> 2, wc = wid & 3;

    // XCD-bijective swizzle; nwg = 512 = 8*64, n-fastest (2 n-blocks/panel).
    const int q       = (int)gridDim.x >> 3;
    const int logical = ((int)blockIdx.x & 7) * q + ((int)blockIdx.x >> 3);
    const int mb = logical >> 1, nbk = logical & 1;
    const long mBase = (long)mb * 256;
    const int  n0    = nbk * 320;

    const int rr = lane & 15, k8 = lane >> 4;

    // fragment read bases (A f32 [256][128B] XOR-8; B pair-packed)
    int aRd[8], bRd[5];
    {
#pragma unroll
        for (int mf = 0; mf < 8; ++mf) {
            const int row = wr * 128 + mf * 16 + rr;
            aRd[mf] = row * 128 + (((2 * k8) ^ (row & 7)) << 4);
        }
#pragma unroll
        for (int nf = 0; nf < 5; ++nf) {
            const int nrow = wc * 80 + nf * 16 + rr, ln = nrow >> 1;
            bRd[nf] = 32768 + ln * 128 +
                      ((((((nrow & 1) << 2) | k8)) ^ (ln & 7)) << 4);
        }
    }

    // staging sources (inverse-swizzled), linear gll dests (R11-proven)
    const float* srcAf;
    {
        const int row = t >> 3, kq = (t & 7) ^ ((t >> 3) & 7);
        srcAf = Ain + (mBase + row) * (long)K + kq * 4;
    }
    const half_t* srcB;
    {
        const int line = t >> 3, orig = (t & 7) ^ (line & 7);
        const int nrow = 2 * line + (orig >> 2), kq = orig & 3;
        srcB = Bw + (size_t)(n0 + nrow) * K + kq * 8;
    }

    auto STAGE_A01 = [&](int k, int sb) {
        const size_t ko = (size_t)k * 32;
        gll16(srcAf + ko, &lds[sb + t * 16]);
        gll16(srcAf + ko + (size_t)64 * K, &lds[sb + (t + 512) * 16]);
    };
    auto STAGE_A23_B = [&](int k, int sb) {
        const size_t ko = (size_t)k * 32;
        gll16(srcAf + ko + (size_t)128 * K, &lds[sb + (t + 1024) * 16]);
        gll16(srcAf + ko + (size_t)192 * K, &lds[sb + (t + 1536) * 16]);
        gll16(srcB + ko,                    &lds[sb + 32768 + t * 16]);
        gll16(srcB + ko + (size_t)128 * K,  &lds[sb + 32768 + (t + 512) * 16]);
        if (t < 256)
            gll16(srcB + ko + (size_t)256 * K,
                  &lds[sb + 32768 + (t + 1024) * 16]);
    };

    f32x4 acc[8][5];
#pragma unroll
    for (int mf = 0; mf < 8; ++mf)
#pragma unroll
        for (int nf = 0; nf < 5; ++nf) {
            f32x4 z = {0.f, 0.f, 0.f, 0.f};
            acc[mf][nf] = z;
        }

    // prologue: L(0)->slab0, L(1)->slab1 (monotone order)
    STAGE_A01(0, 0); STAGE_A23_B(0, 0); SB();
    STAGE_A01(1, SLAB); STAGE_A23_B(1, SLAB); SB();

    for (int ks = 0; ks < NK; ++ks) {
        const int cb  = (ks % 3) * SLAB;
        const int nsb = ((ks + 2) % 3) * SLAB;
        const bool st = (ks + 2) < NK;
        // entry: retire own L(ks), keep L(ks+1) in flight
        if (ks + 1 < NK) {
            if (wid < 4) asm volatile("s_waitcnt vmcnt(7)" ::: "memory");
            else         asm volatile("s_waitcnt vmcnt(6)" ::: "memory");
        } else {
            asm volatile("s_waitcnt vmcnt(0)" ::: "memory");
        }
        __builtin_amdgcn_s_barrier();   // READY: slab ks staged by ALL waves;
                                        // all reads of slab ks-1 complete
        f16x8 bv[5];
        // ---- phase 0: A-half 0 + B reads, stage A01(ks+2), MFMA 20 ----
        {
            float4v alo[4], ahi[4];
#pragma unroll
            for (int m2 = 0; m2 < 4; ++m2) {
                alo[m2] = *(const float4v*)(&lds[cb + aRd[m2]]);
                ahi[m2] = *(const float4v*)(&lds[cb + (aRd[m2] ^ 16)]);
            }
#pragma unroll
            for (int nf = 0; nf < 5; ++nf)
                bv[nf] = *(const f16x8*)(&lds[cb + bRd[nf]]);
            if (st) STAGE_A01(ks + 2, nsb);
            SB();
            asm volatile("s_waitcnt lgkmcnt(0)" ::: "memory");
            SB();                                   // rule 18
            f16x8 av[4];
#pragma unroll
            for (int m2 = 0; m2 < 4; ++m2) {
                f16x8 h;
#pragma unroll
                for (int i = 0; i < 4; ++i) {
                    h[i]     = (half_t)alo[m2][i];
                    h[i + 4] = (half_t)ahi[m2][i];
                }
                av[m2] = h;
            }
            __builtin_amdgcn_s_setprio(1);
#pragma unroll
            for (int m2 = 0; m2 < 4; ++m2)
#pragma unroll
                for (int nf = 0; nf < 5; ++nf)
                    acc[m2][nf] = __builtin_amdgcn_mfma_f32_16x16x32_f16(
                        av[m2], bv[nf], acc[m2][nf], 0, 0, 0);
            __builtin_amdgcn_s_setprio(0);
            SB();
        }
        // ---- phase 1: A-half 1 reads, stage A23+B(ks+2), MFMA 20 ----
        {
            float4v alo[4], ahi[4];
#pragma unroll
            for (int m2 = 0; m2 < 4; ++m2) {
                alo[m2] = *(const float4v*)(&lds[cb + aRd[4 + m2]]);
                ahi[m2] = *(const float4v*)(&lds[cb + (aRd[4 + m2] ^ 16)]);
            }
            if (st) STAGE_A23_B(ks + 2, nsb);
            SB();
            asm volatile("s_waitcnt lgkmcnt(0)" ::: "memory");
            SB();                                   // rule 18
            f16x8 av[4];
#pragma unroll
            for (int m2 = 0; m2 < 4; ++m2) {
                f16x8 h;
#pragma unroll
                for (int i = 0; i < 4; ++i) {
                    h[i]     = (half_t)alo[m2][i];
                    h[i + 4] = (half_t)ahi[m2][i];
                }
                av[m2] = h;
            }
            __builtin_amdgcn_s_setprio(1);
#pragma unroll
            for (int m2 = 0; m2 < 4; ++m2)
#pragma unroll
                for (int nf = 0; nf < 5; ++nf)
                    acc[4 + m2][nf] = __builtin_amdgcn_mfma_f32_16x16x32_f16(
                        av[m2], bv[nf], acc[4 + m2][nf], 0, 0, 0);
            __builtin_amdgcn_s_setprio(0);
            SB();
        }
    }

    // epilogue: C/D frag col=lane&15, row=(lane>>4)*4+j
    const int crow0 = (lane >> 4) * 4;
    const int ccol  = lane & 15;
#pragma unroll
    for (int mf = 0; mf < 8; ++mf)
#pragma unroll
        for (int nf = 0; nf < 5; ++nf)
#pragma unroll
            for (int j = 0; j < 4; ++j) {
                const long row = mBase + wr * 128 + mf * 16 + crow0 + j;
                const int  col = n0 + wc * 80 + nf * 16 + ccol;
                Cout[row * HID + col] = (half_t)gelu_fast(acc[mf][nf][j]);
            }
}

// ---------- GEMM2 (+ fused layer 3), R13-proven, unchanged ----------
template <int K>
__global__ __launch_bounds__(512, 2) void gemm2_fused(
    const half_t* __restrict__ Ain, const half_t* __restrict__ Bw,
    const float* __restrict__ W3, float* __restrict__ Pout) {
    constexpr int NK     = K / 32;                    // 20
    constexpr int ABYTES = 16384;
    constexpr int SLAB   = ABYTES + 20480;
    __shared__ __align__(16) char lds[3 * SLAB];      // 108KB

    const int t = threadIdx.x, lane = t & 63, wid = t >> 6;
    const int wr = wid >> 2, wc = wid & 3;

    const int q       = (int)gridDim.x >> 3;
    const int logical = ((int)blockIdx.x & 7) * q + ((int)blockIdx.x >> 3);
    const int mb = logical >> 1, nbk = logical & 1;
    const long mBase = (long)mb * 256;
    const int  n0    = nbk * 320;

    const int rr = lane & 15, k8 = lane >> 4;

    int aBase0 = 0, bBase = 0;
    {
        const int row = wr * 128 + rr, ln = row >> 1;
        aBase0 = ln * 128 + ((((((row & 1) << 2) | k8)) ^ (ln & 7)) << 4);
        const int nrow = wc * 80 + rr, lnb = nrow >> 1;
        bBase = ABYTES + lnb * 128 +
                ((((((nrow & 1) << 2) | k8)) ^ (lnb & 7)) << 4);
    }

    const half_t* srcAh;
    {
        const int line = t >> 3, orig = (t & 7) ^ (line & 7);
        const int row = 2 * line + (orig >> 2), kq = orig & 3;
        srcAh = Ain + (mBase + row) * (long)K + kq * 8;
    }
    const half_t* srcB;
    {
        const int line = t >> 3, orig = (t & 7) ^ (line & 7);
        const int nrow = 2 * line + (orig >> 2), kq = orig & 3;
        srcB = Bw + (size_t)(n0 + nrow) * K + kq * 8;
    }

    auto STAGE = [&](int k, int sb) {
        const size_t ko = (size_t)k * 32;
#pragma unroll
        for (int r = 0; r < 2; ++r)
            gll16(srcAh + ko + (size_t)r * 128 * K,
                  &lds[sb + (t + r * 512) * 16]);
#pragma unroll
        for (int r = 0; r < 2; ++r)
            gll16(srcB + ko + (size_t)r * 128 * K,
                  &lds[sb + ABYTES + (t + r * 512) * 16]);
        if (t < 256)
            gll16(srcB + ko + (size_t)2 * 128 * K,
                  &lds[sb + ABYTES + (t + 1024) * 16]);
    };

    f32x4 acc[8][5];
#pragma unroll
    for (int mf = 0; mf < 8; ++mf)
#pragma unroll
        for (int nf = 0; nf < 5; ++nf) {
            f32x4 z = {0.f, 0.f, 0.f, 0.f};
            acc[mf][nf] = z;
        }

    STAGE(0, 0); SB();
    STAGE(1, SLAB); SB();

    for (int ks = 0; ks < NK; ++ks) {
        if (ks + 1 < NK) {
            if (wid < 4) asm volatile("s_waitcnt vmcnt(5)" ::: "memory");
            else         asm volatile("s_waitcnt vmcnt(4)" ::: "memory");
        } else {
            asm volatile("s_waitcnt vmcnt(0)" ::: "memory");
        }
        __builtin_amdgcn_s_barrier();
        const int cb = (ks % 3) * SLAB;
        if (ks + 2 < NK) { STAGE(ks + 2, ((ks + 2) % 3) * SLAB); SB(); }

        f16x8 bv[5];
#pragma unroll
        for (int nf = 0; nf < 5; ++nf)
            bv[nf] = *(const f16x8*)(&lds[cb + bBase + nf * 1024]);
        f16x8 av[8];
#pragma unroll
        for (int mf = 0; mf < 8; ++mf)
            av[mf] = *(const f16x8*)(&lds[cb + aBase0 + mf * 1024]);
#pragma unroll
        for (int mf = 0; mf < 8; ++mf)
#pragma unroll
            for (int nf = 0; nf < 5; ++nf)
                acc[mf][nf] = __builtin_amdgcn_mfma_f32_16x16x32_f16(
                    av[mf], bv[nf], acc[mf][nf], 0, 0, 0);
    }

    // fused layer 3 epilogue (R13-proven)
    const int crow0 = (lane >> 4) * 4;
    const int ccol  = lane & 15;
    float w3[OUT_F][5];
#pragma unroll
    for (int o = 0; o < OUT_F; ++o)
#pragma unroll
        for (int nf = 0; nf < 5; ++nf)
            w3[o][nf] = W3[o * HID + n0 + wc * 80 + nf * 16 + ccol];
    float* slice = Pout + (size_t)(nbk * 4 + wc) * NBATCH * OUT_F;
#pragma unroll
    for (int mf = 0; mf < 8; ++mf)
#pragma unroll
        for (int j = 0; j < 4; ++j) {
            float p[OUT_F];
#pragma unroll
            for (int o = 0; o < OUT_F; ++o) p[o] = 0.f;
#pragma unroll
            for (int nf = 0; nf < 5; ++nf) {
                const float v = gelu_fast(acc[mf][nf][j]);
#pragma unroll
                for (int o = 0; o < OUT_F; ++o) p[o] += v * w3[o][nf];
            }
#pragma unroll
            for (int mask = 1; mask < 16; mask <<= 1)
#pragma unroll
                for (int o = 0; o < OUT_F; ++o)
                    p[o] += __shfl_xor(p[o], mask);
            float v = 0.f;
#pragma unroll
            for (int o = 0; o < OUT_F; ++o) v = (ccol == o) ? p[o] : v;
            const long row = mBase + wr * 128 + mf * 16 + crow0 + j;
            if (ccol < OUT_F) slice[row * OUT_F + ccol] = v;
        }
}

// ---------- final: out = sum of 8 partial slices ----------
__global__ void k_final(const float* __restrict__ P, float* __restrict__ out) {
    const int n = NBATCH * OUT_F;
    for (int i = blockIdx.x * blockDim.x + threadIdx.x; i < n;
         i += gridDim.x * blockDim.x) {
        float s0 = P[i]                 + P[(size_t)1 * n + i];
        float s1 = P[(size_t)2 * n + i] + P[(size_t)3 * n + i];
        float s2 = P[(size_t)4 * n + i] + P[(size_t)5 * n + i];
        float s3 = P[(size_t)6 * n + i] + P[(size_t)7 * n + i];
        out[i] = (s0 + s1) + (s2 + s3);
    }
}

// ---------- launch ----------

extern "C" void kernel_launch(void* const* d_in, const int* in_sizes, int n_in,
                              void* d_out, int out_size, void* d_ws, size_t ws_size,
                              hipStream_t stream) {
    const float* x  = (const float*)d_in[0];
    const float* W1 = (const float*)d_in[1];
    const float* W2 = (const float*)d_in[2];
    const float* W3 = (const float*)d_in[3];
    const void*  m1 = d_in[4];
    const void*  m2 = d_in[5];
    const void*  m3 = d_in[6];
    float* out = (float*)d_out;

    char* ws = (char*)d_ws;
    int*    flags = (int*)ws;
    half_t* W1h = (half_t*)(ws + 256);                      // 640*1536*2
    half_t* W2h = (half_t*)(ws + 256 + 1966080);            // 640*640*2
    float*  W3m = (float*)(ws + 256 + 1966080 + 819200);    // 25600
    half_t* h1  = (half_t*)(ws + 256 + 1966080 + 819200 + 25600);
    float*  Pp  = (float*)((char*)h1 + (size_t)NBATCH * HID * 2);  // 8*655360*4

    hipMemsetAsync(flags, 0, 8, stream);
    k_detect<<<64, 256, 0, stream>>>((const unsigned*)m1, 65536, flags);
    k_mask_all<<<1024, 256, 0, stream>>>(W1, W2, W3, m1, m2, m3, W1h, W2h, W3m, flags);

    gemm1_tall<<<512, 512, 0, stream>>>(x, W1h, h1);
    gemm2_fused<HID><<<512, 512, 0, stream>>>(h1, W2h, W3m, Pp);
    k_final<<<1024, 256, 0, stream>>>(Pp, out);
}

// Round 19
// 288.771 us; speedup vs baseline: 3.4124x; 1.0996x over previous
//
#include <hip/hip_runtime.h>
#include <hip/hip_fp16.h>
#include <math.h>

typedef _Float16 half_t;
typedef __attribute__((ext_vector_type(8))) _Float16 f16x8;  // MFMA A/B frag
typedef __attribute__((ext_vector_type(4))) float   f32x4;   // MFMA C/D frag
typedef __attribute__((ext_vector_type(4))) float   float4v;

#define IN_F   1536
#define HID    640
#define OUT_F  10
#define NBATCH 65536

#define SB() __builtin_amdgcn_sched_barrier(0)

// ---------- helpers ----------

__device__ __forceinline__ void gll16(const void* g, const void* l) {
    __builtin_amdgcn_global_load_lds(
        (const __attribute__((address_space(1))) unsigned*)g,
        (__attribute__((address_space(3))) unsigned*)l, 16, 0, 0);
}

// exact-GELU via A&S 7.1.26 erf poly (|eps|<=1.5e-7, noise vs f16 rounding)
__device__ __forceinline__ float gelu_fast(float z) {
    float x  = 0.70710678118654752f * z;
    float ax = fabsf(x);
    float t  = 1.0f / (1.0f + 0.3275911f * ax);
    float p  = t * (0.254829592f +
               t * (-0.284496736f +
               t * (1.421413741f +
               t * (-1.453152027f +
               t * 1.061405429f))));
    float e  = __expf(-ax * ax);
    float er = 1.0f - p * e;
    er = (x < 0.0f) ? -er : er;
    return 0.5f * z * (1.0f + er);
}

// ---------- prep ----------

__global__ void k_detect(const unsigned* __restrict__ m, int nDwords, int* flags) {
    int f = 0, g = 0;
    for (int i = blockIdx.x * blockDim.x + threadIdx.x; i < nDwords;
         i += gridDim.x * blockDim.x) {
        unsigned d = m[i];
        f |= (d == 0x3F800000u);
        g |= (d != 0u) & (d != 1u) & (d != 0x3F800000u);
    }
    if (f) atomicOr(&flags[0], 1);
    if (g) atomicOr(&flags[1], 1);
}

__device__ __forceinline__ bool mask_at(const void* mask, int i, int isB, int isF) {
    if (isB) return ((const unsigned char*)mask)[i] != 0;
    if (isF) return ((const float*)mask)[i] != 0.0f;
    return ((const int*)mask)[i] != 0;
}

__global__ void k_mask_all(const float* __restrict__ W1, const float* __restrict__ W2,
                           const float* __restrict__ W3,
                           const void* __restrict__ m1, const void* __restrict__ m2,
                           const void* __restrict__ m3,
                           half_t* __restrict__ W1h, half_t* __restrict__ W2h,
                           float* __restrict__ W3m, const int* __restrict__ flags) {
    const int isB = flags[1], isF = flags[0];
    const int N1 = HID * IN_F, N2 = HID * HID, N3 = OUT_F * HID;
    const int NT = N1 + N2 + N3;
    for (int i = blockIdx.x * blockDim.x + threadIdx.x; i < NT;
         i += gridDim.x * blockDim.x) {
        if (i < N1) {
            W1h[i] = mask_at(m1, i, isB, isF) ? (half_t)W1[i] : (half_t)0.0f;
        } else if (i < N1 + N2) {
            int j = i - N1;
            W2h[j] = mask_at(m2, j, isB, isF) ? (half_t)W2[j] : (half_t)0.0f;
        } else {
            int j = i - N1 - N2;
            W3m[j] = mask_at(m3, j, isB, isF) ? W3[j] : 0.0f;
        }
    }
}

// ---------- GEMM1: R11 ring, 3-phase fine interleave (R18 protocol) ----------
// h1[m][n] = gelu( sum_k x[m][k] * W1[n][k] ), f16 out.
// BM=256, BN=320, BK=32. 512 thr = 8 waves (2m x 4n), per-wave C = 128x80,
// acc[8][5]=160. LDS 3-slab ring 156KB. Protocol (R11/R18-proven): entry
// vmcnt(7/6) retires own L(ks); ONE READY barrier (slab ks staged by ALL
// waves; reads of slab ks-1 complete -> STAGE(ks+2) into it is safe); ALL
// reads of slab ks strictly after the barrier. Step = 3 phases, staging
// spread 2/2/3 gll between MFMA clusters (15/15/10), monotone issue order.
__global__ __launch_bounds__(512, 2) void gemm1_tall(
    const float* __restrict__ Ain, const half_t* __restrict__ Bw,
    half_t* __restrict__ Cout) {
    constexpr int K    = IN_F;
    constexpr int NK   = K / 32;                     // 48
    constexpr int SLAB = 32768 + 20480;              // A f32 32KB + B 20KB
    __shared__ __align__(16) char lds[3 * SLAB];     // 156KB

    const int t = threadIdx.x, lane = t & 63, wid = t >> 6;
    const int wr = wid >> 2, wc = wid & 3;

    // XCD-bijective swizzle; nwg = 512 = 8*64, n-fastest (2 n-blocks/panel).
    const int q       = (int)gridDim.x >> 3;
    const int logical = ((int)blockIdx.x & 7) * q + ((int)blockIdx.x >> 3);
    const int mb = logical >> 1, nbk = logical & 1;
    const long mBase = (long)mb * 256;
    const int  n0    = nbk * 320;

    const int rr = lane & 15, k8 = lane >> 4;

    // fragment read bases (A f32 [256][128B] XOR-8; B pair-packed)
    int aRd[8], bRd[5];
    {
#pragma unroll
        for (int mf = 0; mf < 8; ++mf) {
            const int row = wr * 128 + mf * 16 + rr;
            aRd[mf] = row * 128 + (((2 * k8) ^ (row & 7)) << 4);
        }
#pragma unroll
        for (int nf = 0; nf < 5; ++nf) {
            const int nrow = wc * 80 + nf * 16 + rr, ln = nrow >> 1;
            bRd[nf] = 32768 + ln * 128 +
                      ((((((nrow & 1) << 2) | k8)) ^ (ln & 7)) << 4);
        }
    }

    // staging sources (inverse-swizzled), linear gll dests (R11-proven)
    const float* srcAf;
    {
        const int row = t >> 3, kq = (t & 7) ^ ((t >> 3) & 7);
        srcAf = Ain + (mBase + row) * (long)K + kq * 4;
    }
    const half_t* srcB;
    {
        const int line = t >> 3, orig = (t & 7) ^ (line & 7);
        const int nrow = 2 * line + (orig >> 2), kq = orig & 3;
        srcB = Bw + (size_t)(n0 + nrow) * K + kq * 8;
    }

    auto STAGE_A01 = [&](int k, int sb) {
        const size_t ko = (size_t)k * 32;
        gll16(srcAf + ko, &lds[sb + t * 16]);
        gll16(srcAf + ko + (size_t)64 * K, &lds[sb + (t + 512) * 16]);
    };
    auto STAGE_A23 = [&](int k, int sb) {
        const size_t ko = (size_t)k * 32;
        gll16(srcAf + ko + (size_t)128 * K, &lds[sb + (t + 1024) * 16]);
        gll16(srcAf + ko + (size_t)192 * K, &lds[sb + (t + 1536) * 16]);
    };
    auto STAGE_B = [&](int k, int sb) {
        const size_t ko = (size_t)k * 32;
        gll16(srcB + ko,                   &lds[sb + 32768 + t * 16]);
        gll16(srcB + ko + (size_t)128 * K, &lds[sb + 32768 + (t + 512) * 16]);
        if (t < 256)
            gll16(srcB + ko + (size_t)256 * K,
                  &lds[sb + 32768 + (t + 1024) * 16]);
    };

    f32x4 acc[8][5];
#pragma unroll
    for (int mf = 0; mf < 8; ++mf)
#pragma unroll
        for (int nf = 0; nf < 5; ++nf) {
            f32x4 z = {0.f, 0.f, 0.f, 0.f};
            acc[mf][nf] = z;
        }

    // prologue: L(0)->slab0, L(1)->slab1 (monotone order)
    STAGE_A01(0, 0); STAGE_A23(0, 0); STAGE_B(0, 0); SB();
    STAGE_A01(1, SLAB); STAGE_A23(1, SLAB); STAGE_B(1, SLAB); SB();

    for (int ks = 0; ks < NK; ++ks) {
        const int cb  = (ks % 3) * SLAB;
        const int nsb = ((ks + 2) % 3) * SLAB;
        const bool st = (ks + 2) < NK;
        if (ks + 1 < NK) {
            if (wid < 4) asm volatile("s_waitcnt vmcnt(7)" ::: "memory");
            else         asm volatile("s_waitcnt vmcnt(6)" ::: "memory");
        } else {
            asm volatile("s_waitcnt vmcnt(0)" ::: "memory");
        }
        __builtin_amdgcn_s_barrier();   // READY: slab ks staged by ALL waves

        f16x8 bv[5];
        // ---- phase 0: bv + A frags 0-2; stage A01(ks+2); 15 MFMA ----
        {
            float4v alo[3], ahi[3];
#pragma unroll
            for (int m2 = 0; m2 < 3; ++m2) {
                alo[m2] = *(const float4v*)(&lds[cb + aRd[m2]]);
                ahi[m2] = *(const float4v*)(&lds[cb + (aRd[m2] ^ 16)]);
            }
#pragma unroll
            for (int nf = 0; nf < 5; ++nf)
                bv[nf] = *(const f16x8*)(&lds[cb + bRd[nf]]);
            if (st) STAGE_A01(ks + 2, nsb);
            SB();
            asm volatile("s_waitcnt lgkmcnt(0)" ::: "memory");
            SB();                                   // rule 18
            f16x8 av[3];
#pragma unroll
            for (int m2 = 0; m2 < 3; ++m2) {
                f16x8 h;
#pragma unroll
                for (int i = 0; i < 4; ++i) {
                    h[i]     = (half_t)alo[m2][i];
                    h[i + 4] = (half_t)ahi[m2][i];
                }
                av[m2] = h;
            }
            __builtin_amdgcn_s_setprio(1);
#pragma unroll
            for (int m2 = 0; m2 < 3; ++m2)
#pragma unroll
                for (int nf = 0; nf < 5; ++nf)
                    acc[m2][nf] = __builtin_amdgcn_mfma_f32_16x16x32_f16(
                        av[m2], bv[nf], acc[m2][nf], 0, 0, 0);
            __builtin_amdgcn_s_setprio(0);
            SB();
        }
        // ---- phase 1: A frags 3-5; stage A23(ks+2); 15 MFMA ----
        {
            float4v alo[3], ahi[3];
#pragma unroll
            for (int m2 = 0; m2 < 3; ++m2) {
                alo[m2] = *(const float4v*)(&lds[cb + aRd[3 + m2]]);
                ahi[m2] = *(const float4v*)(&lds[cb + (aRd[3 + m2] ^ 16)]);
            }
            if (st) STAGE_A23(ks + 2, nsb);
            SB();
            asm volatile("s_waitcnt lgkmcnt(0)" ::: "memory");
            SB();
            f16x8 av[3];
#pragma unroll
            for (int m2 = 0; m2 < 3; ++m2) {
                f16x8 h;
#pragma unroll
                for (int i = 0; i < 4; ++i) {
                    h[i]     = (half_t)alo[m2][i];
                    h[i + 4] = (half_t)ahi[m2][i];
                }
                av[m2] = h;
            }
            __builtin_amdgcn_s_setprio(1);
#pragma unroll
            for (int m2 = 0; m2 < 3; ++m2)
#pragma unroll
                for (int nf = 0; nf < 5; ++nf)
                    acc[3 + m2][nf] = __builtin_amdgcn_mfma_f32_16x16x32_f16(
                        av[m2], bv[nf], acc[3 + m2][nf], 0, 0, 0);
            __builtin_amdgcn_s_setprio(0);
            SB();
        }
        // ---- phase 2: A frags 6-7; stage B(ks+2); 10 MFMA ----
        {
            float4v alo[2], ahi[2];
#pragma unroll
            for (int m2 = 0; m2 < 2; ++m2) {
                alo[m2] = *(const float4v*)(&lds[cb + aRd[6 + m2]]);
                ahi[m2] = *(const float4v*)(&lds[cb + (aRd[6 + m2] ^ 16)]);
            }
            if (st) STAGE_B(ks + 2, nsb);
            SB();
            asm volatile("s_waitcnt lgkmcnt(0)" ::: "memory");
            SB();
            f16x8 av[2];
#pragma unroll
            for (int m2 = 0; m2 < 2; ++m2) {
                f16x8 h;
#pragma unroll
                for (int i = 0; i < 4; ++i) {
                    h[i]     = (half_t)alo[m2][i];
                    h[i + 4] = (half_t)ahi[m2][i];
                }
                av[m2] = h;
            }
            __builtin_amdgcn_s_setprio(1);
#pragma unroll
            for (int m2 = 0; m2 < 2; ++m2)
#pragma unroll
                for (int nf = 0; nf < 5; ++nf)
                    acc[6 + m2][nf] = __builtin_amdgcn_mfma_f32_16x16x32_f16(
                        av[m2], bv[nf], acc[6 + m2][nf], 0, 0, 0);
            __builtin_amdgcn_s_setprio(0);
            SB();
        }
    }

    // epilogue: C/D frag col=lane&15, row=(lane>>4)*4+j
    const int crow0 = (lane >> 4) * 4;
    const int ccol  = lane & 15;
#pragma unroll
    for (int mf = 0; mf < 8; ++mf)
#pragma unroll
        for (int nf = 0; nf < 5; ++nf)
#pragma unroll
            for (int j = 0; j < 4; ++j) {
                const long row = mBase + wr * 128 + mf * 16 + crow0 + j;
                const int  col = n0 + wc * 80 + nf * 16 + ccol;
                Cout[row * HID + col] = (half_t)gelu_fast(acc[mf][nf][j]);
            }
}

// ---------- GEMM2 (+ fused layer 3), R13 ring + 2-phase interleave ----------
template <int K>
__global__ __launch_bounds__(512, 2) void gemm2_fused(
    const half_t* __restrict__ Ain, const half_t* __restrict__ Bw,
    const float* __restrict__ W3, float* __restrict__ Pout) {
    constexpr int NK     = K / 32;                    // 20
    constexpr int ABYTES = 16384;
    constexpr int SLAB   = ABYTES + 20480;
    __shared__ __align__(16) char lds[3 * SLAB];      // 108KB

    const int t = threadIdx.x, lane = t & 63, wid = t >> 6;
    const int wr = wid >> 2, wc = wid & 3;

    const int q       = (int)gridDim.x >> 3;
    const int logical = ((int)blockIdx.x & 7) * q + ((int)blockIdx.x >> 3);
    const int mb = logical >> 1, nbk = logical & 1;
    const long mBase = (long)mb * 256;
    const int  n0    = nbk * 320;

    const int rr = lane & 15, k8 = lane >> 4;

    int aBase0 = 0, bBase = 0;
    {
        const int row = wr * 128 + rr, ln = row >> 1;
        aBase0 = ln * 128 + ((((((row & 1) << 2) | k8)) ^ (ln & 7)) << 4);
        const int nrow = wc * 80 + rr, lnb = nrow >> 1;
        bBase = ABYTES + lnb * 128 +
                ((((((nrow & 1) << 2) | k8)) ^ (lnb & 7)) << 4);
    }

    const half_t* srcAh;
    {
        const int line = t >> 3, orig = (t & 7) ^ (line & 7);
        const int row = 2 * line + (orig >> 2), kq = orig & 3;
        srcAh = Ain + (mBase + row) * (long)K + kq * 8;
    }
    const half_t* srcB;
    {
        const int line = t >> 3, orig = (t & 7) ^ (line & 7);
        const int nrow = 2 * line + (orig >> 2), kq = orig & 3;
        srcB = Bw + (size_t)(n0 + nrow) * K + kq * 8;
    }

    auto STAGE_A = [&](int k, int sb) {
        const size_t ko = (size_t)k * 32;
#pragma unroll
        for (int r = 0; r < 2; ++r)
            gll16(srcAh + ko + (size_t)r * 128 * K,
                  &lds[sb + (t + r * 512) * 16]);
    };
    auto STAGE_B = [&](int k, int sb) {
        const size_t ko = (size_t)k * 32;
#pragma unroll
        for (int r = 0; r < 2; ++r)
            gll16(srcB + ko + (size_t)r * 128 * K,
                  &lds[sb + ABYTES + (t + r * 512) * 16]);
        if (t < 256)
            gll16(srcB + ko + (size_t)2 * 128 * K,
                  &lds[sb + ABYTES + (t + 1024) * 16]);
    };

    f32x4 acc[8][5];
#pragma unroll
    for (int mf = 0; mf < 8; ++mf)
#pragma unroll
        for (int nf = 0; nf < 5; ++nf) {
            f32x4 z = {0.f, 0.f, 0.f, 0.f};
            acc[mf][nf] = z;
        }

    STAGE_A(0, 0); STAGE_B(0, 0); SB();
    STAGE_A(1, SLAB); STAGE_B(1, SLAB); SB();

    for (int ks = 0; ks < NK; ++ks) {
        const int cb  = (ks % 3) * SLAB;
        const int nsb = ((ks + 2) % 3) * SLAB;
        const bool st = (ks + 2) < NK;
        if (ks + 1 < NK) {
            if (wid < 4) asm volatile("s_waitcnt vmcnt(5)" ::: "memory");
            else         asm volatile("s_waitcnt vmcnt(4)" ::: "memory");
        } else {
            asm volatile("s_waitcnt vmcnt(0)" ::: "memory");
        }
        __builtin_amdgcn_s_barrier();   // READY(ks)

        f16x8 bv[5];
        // ---- phase 0: bv + A frags 0-3; stage A(ks+2); 20 MFMA ----
        {
            f16x8 av[4];
#pragma unroll
            for (int m2 = 0; m2 < 4; ++m2)
                av[m2] = *(const f16x8*)(&lds[cb + aBase0 + m2 * 1024]);
#pragma unroll
            for (int nf = 0; nf < 5; ++nf)
                bv[nf] = *(const f16x8*)(&lds[cb + bBase + nf * 1024]);
            if (st) STAGE_A(ks + 2, nsb);
            SB();
            asm volatile("s_waitcnt lgkmcnt(0)" ::: "memory");
            SB();                                   // rule 18
            __builtin_amdgcn_s_setprio(1);
#pragma unroll
            for (int m2 = 0; m2 < 4; ++m2)
#pragma unroll
                for (int nf = 0; nf < 5; ++nf)
                    acc[m2][nf] = __builtin_amdgcn_mfma_f32_16x16x32_f16(
                        av[m2], bv[nf], acc[m2][nf], 0, 0, 0);
            __builtin_amdgcn_s_setprio(0);
            SB();
        }
        // ---- phase 1: A frags 4-7; stage B(ks+2); 20 MFMA ----
        {
            f16x8 av[4];
#pragma unroll
            for (int m2 = 0; m2 < 4; ++m2)
                av[m2] = *(const f16x8*)(&lds[cb + aBase0 + (4 + m2) * 1024]);
            if (st) STAGE_B(ks + 2, nsb);
            SB();
            asm volatile("s_waitcnt lgkmcnt(0)" ::: "memory");
            SB();
            __builtin_amdgcn_s_setprio(1);
#pragma unroll
            for (int m2 = 0; m2 < 4; ++m2)
#pragma unroll
                for (int nf = 0; nf < 5; ++nf)
                    acc[4 + m2][nf] = __builtin_amdgcn_mfma_f32_16x16x32_f16(
                        av[m2], bv[nf], acc[4 + m2][nf], 0, 0, 0);
            __builtin_amdgcn_s_setprio(0);
            SB();
        }
    }

    // fused layer 3 epilogue (R13-proven)
    const int crow0 = (lane >> 4) * 4;
    const int ccol  = lane & 15;
    float w3[OUT_F][5];
#pragma unroll
    for (int o = 0; o < OUT_F; ++o)
#pragma unroll
        for (int nf = 0; nf < 5; ++nf)
            w3[o][nf] = W3[o * HID + n0 + wc * 80 + nf * 16 + ccol];
    float* slice = Pout + (size_t)(nbk * 4 + wc) * NBATCH * OUT_F;
#pragma unroll
    for (int mf = 0; mf < 8; ++mf)
#pragma unroll
        for (int j = 0; j < 4; ++j) {
            float p[OUT_F];
#pragma unroll
            for (int o = 0; o < OUT_F; ++o) p[o] = 0.f;
#pragma unroll
            for (int nf = 0; nf < 5; ++nf) {
                const float v = gelu_fast(acc[mf][nf][j]);
#pragma unroll
                for (int o = 0; o < OUT_F; ++o) p[o] += v * w3[o][nf];
            }
#pragma unroll
            for (int mask = 1; mask < 16; mask <<= 1)
#pragma unroll
                for (int o = 0; o < OUT_F; ++o)
                    p[o] += __shfl_xor(p[o], mask);
            float v = 0.f;
#pragma unroll
            for (int o = 0; o < OUT_F; ++o) v = (ccol == o) ? p[o] : v;
            const long row = mBase + wr * 128 + mf * 16 + crow0 + j;
            if (ccol < OUT_F) slice[row * OUT_F + ccol] = v;
        }
}

// ---------- final: out = sum of 8 partial slices ----------
__global__ void k_final(const float* __restrict__ P, float* __restrict__ out) {
    const int n = NBATCH * OUT_F;
    for (int i = blockIdx.x * blockDim.x + threadIdx.x; i < n;
         i += gridDim.x * blockDim.x) {
        float s0 = P[i]                 + P[(size_t)1 * n + i];
        float s1 = P[(size_t)2 * n + i] + P[(size_t)3 * n + i];
        float s2 = P[(size_t)4 * n + i] + P[(size_t)5 * n + i];
        float s3 = P[(size_t)6 * n + i] + P[(size_t)7 * n + i];
        out[i] = (s0 + s1) + (s2 + s3);
    }
}

// ---------- launch ----------

extern "C" void kernel_launch(void* const* d_in, const int* in_sizes, int n_in,
                              void* d_out, int out_size, void* d_ws, size_t ws_size,
                              hipStream_t stream) {
    const float* x  = (const float*)d_in[0];
    const float* W1 = (const float*)d_in[1];
    const float* W2 = (const float*)d_in[2];
    const float* W3 = (const float*)d_in[3];
    const void*  m1 = d_in[4];
    const void*  m2 = d_in[5];
    const void*  m3 = d_in[6];
    float* out = (float*)d_out;

    char* ws = (char*)d_ws;
    int*    flags = (int*)ws;
    half_t* W1h = (half_t*)(ws + 256);                      // 640*1536*2
    half_t* W2h = (half_t*)(ws + 256 + 1966080);            // 640*640*2
    float*  W3m = (float*)(ws + 256 + 1966080 + 819200);    // 25600
    half_t* h1  = (half_t*)(ws + 256 + 1966080 + 819200 + 25600);
    float*  Pp  = (float*)((char*)h1 + (size_t)NBATCH * HID * 2);  // 8*655360*4

    hipMemsetAsync(flags, 0, 8, stream);
    k_detect<<<64, 256, 0, stream>>>((const unsigned*)m1, 65536, flags);
    k_mask_all<<<1024, 256, 0, stream>>>(W1, W2, W3, m1, m2, m3, W1h, W2h, W3m, flags);

    gemm1_tall<<<512, 512, 0, stream>>>(x, W1h, h1);
    gemm2_fused<HID><<<512, 512, 0, stream>>>(h1, W2h, W3m, Pp);
    k_final<<<1024, 256, 0, stream>>>(Pp, out);
}

// Round 20
// 287.826 us; speedup vs baseline: 3.4236x; 1.0033x over previous
//
#include <hip/hip_runtime.h>
#include <hip/hip_fp16.h>
#include <math.h>

typedef _Float16 half_t;
typedef __attribute__((ext_vector_type(8))) _Float16 f16x8;  // MFMA A/B frag
typedef __attribute__((ext_vector_type(4))) float   f32x4;   // MFMA C/D frag
typedef __attribute__((ext_vector_type(4))) float   float4v;

#define IN_F   1536
#define HID    640
#define OUT_F  10
#define NBATCH 65536

#define SB() __builtin_amdgcn_sched_barrier(0)

// ---------- helpers ----------

__device__ __forceinline__ void gll16(const void* g, const void* l) {
    __builtin_amdgcn_global_load_lds(
        (const __attribute__((address_space(1))) unsigned*)g,
        (__attribute__((address_space(3))) unsigned*)l, 16, 0, 0);
}

// exact-GELU via A&S 7.1.26 erf poly (|eps|<=1.5e-7, noise vs f16 rounding)
__device__ __forceinline__ float gelu_fast(float z) {
    float x  = 0.70710678118654752f * z;
    float ax = fabsf(x);
    float t  = 1.0f / (1.0f + 0.3275911f * ax);
    float p  = t * (0.254829592f +
               t * (-0.284496736f +
               t * (1.421413741f +
               t * (-1.453152027f +
               t * 1.061405429f))));
    float e  = __expf(-ax * ax);
    float er = 1.0f - p * e;
    er = (x < 0.0f) ? -er : er;
    return 0.5f * z * (1.0f + er);
}

// ---------- prep ----------

__global__ void k_detect(const unsigned* __restrict__ m, int nDwords, int* flags) {
    int f = 0, g = 0;
    for (int i = blockIdx.x * blockDim.x + threadIdx.x; i < nDwords;
         i += gridDim.x * blockDim.x) {
        unsigned d = m[i];
        f |= (d == 0x3F800000u);
        g |= (d != 0u) & (d != 1u) & (d != 0x3F800000u);
    }
    if (f) atomicOr(&flags[0], 1);
    if (g) atomicOr(&flags[1], 1);
}

__device__ __forceinline__ bool mask_at(const void* mask, int i, int isB, int isF) {
    if (isB) return ((const unsigned char*)mask)[i] != 0;
    if (isF) return ((const float*)mask)[i] != 0.0f;
    return ((const int*)mask)[i] != 0;
}

__global__ void k_mask_all(const float* __restrict__ W1, const float* __restrict__ W2,
                           const float* __restrict__ W3,
                           const void* __restrict__ m1, const void* __restrict__ m2,
                           const void* __restrict__ m3,
                           half_t* __restrict__ W1h, half_t* __restrict__ W2h,
                           float* __restrict__ W3m, const int* __restrict__ flags) {
    const int isB = flags[1], isF = flags[0];
    const int N1 = HID * IN_F, N2 = HID * HID, N3 = OUT_F * HID;
    const int NT = N1 + N2 + N3;
    for (int i = blockIdx.x * blockDim.x + threadIdx.x; i < NT;
         i += gridDim.x * blockDim.x) {
        if (i < N1) {
            W1h[i] = mask_at(m1, i, isB, isF) ? (half_t)W1[i] : (half_t)0.0f;
        } else if (i < N1 + N2) {
            int j = i - N1;
            W2h[j] = mask_at(m2, j, isB, isF) ? (half_t)W2[j] : (half_t)0.0f;
        } else {
            int j = i - N1 - N2;
            W3m[j] = mask_at(m3, j, isB, isF) ? W3[j] : 0.0f;
        }
    }
}

// ---------- GEMM1: R11 ring, 4-phase fine interleave (R18 protocol) ----------
// h1[m][n] = gelu( sum_k x[m][k] * W1[n][k] ), f16 out.
// BM=256, BN=320, BK=32. 512 thr = 8 waves (2m x 4n), per-wave C = 128x80,
// acc[8][5]=160. LDS 3-slab ring 156KB. Protocol (R11/R18/R19-proven): entry
// vmcnt(7/6) retires own L(ks); ONE READY barrier; ALL reads of slab ks
// strictly after it; STAGE(ks+2) partials interleaved between MFMA clusters,
// monotone issue order (A01,A23,B01,B2 — matches prologue) so counts hold.
// Step = 4 phases: A-frag pairs {01}{23}{45}{67}, 10 MFMA each; stage spread
// 2/2/2/1 gll.
__global__ __launch_bounds__(512, 2) void gemm1_tall(
    const float* __restrict__ Ain, const half_t* __restrict__ Bw,
    half_t* __restrict__ Cout) {
    constexpr int K    = IN_F;
    constexpr int NK   = K / 32;                     // 48
    constexpr int SLAB = 32768 + 20480;              // A f32 32KB + B 20KB
    __shared__ __align__(16) char lds[3 * SLAB];     // 156KB

    const int t = threadIdx.x, lane = t & 63, wid = t >> 6;
    const int wr = wid >> 2, wc = wid & 3;

    // XCD-bijective swizzle; nwg = 512 = 8*64, n-fastest (2 n-blocks/panel).
    const int q       = (int)gridDim.x >> 3;
    const int logical = ((int)blockIdx.x & 7) * q + ((int)blockIdx.x >> 3);
    const int mb = logical >> 1, nbk = logical & 1;
    const long mBase = (long)mb * 256;
    const int  n0    = nbk * 320;

    const int rr = lane & 15, k8 = lane >> 4;

    // fragment read bases (A f32 [256][128B] XOR-8; B pair-packed)
    int aRd[8], bRd[5];
    {
#pragma unroll
        for (int mf = 0; mf < 8; ++mf) {
            const int row = wr * 128 + mf * 16 + rr;
            aRd[mf] = row * 128 + (((2 * k8) ^ (row & 7)) << 4);
        }
#pragma unroll
        for (int nf = 0; nf < 5; ++nf) {
            const int nrow = wc * 80 + nf * 16 + rr, ln = nrow >> 1;
            bRd[nf] = 32768 + ln * 128 +
                      ((((((nrow & 1) << 2) | k8)) ^ (ln & 7)) << 4);
        }
    }

    // staging sources (inverse-swizzled), linear gll dests (R11-proven)
    const float* srcAf;
    {
        const int row = t >> 3, kq = (t & 7) ^ ((t >> 3) & 7);
        srcAf = Ain + (mBase + row) * (long)K + kq * 4;
    }
    const half_t* srcB;
    {
        const int line = t >> 3, orig = (t & 7) ^ (line & 7);
        const int nrow = 2 * line + (orig >> 2), kq = orig & 3;
        srcB = Bw + (size_t)(n0 + nrow) * K + kq * 8;
    }

    auto STAGE_A01 = [&](int k, int sb) {
        const size_t ko = (size_t)k * 32;
        gll16(srcAf + ko, &lds[sb + t * 16]);
        gll16(srcAf + ko + (size_t)64 * K, &lds[sb + (t + 512) * 16]);
    };
    auto STAGE_A23 = [&](int k, int sb) {
        const size_t ko = (size_t)k * 32;
        gll16(srcAf + ko + (size_t)128 * K, &lds[sb + (t + 1024) * 16]);
        gll16(srcAf + ko + (size_t)192 * K, &lds[sb + (t + 1536) * 16]);
    };
    auto STAGE_B01 = [&](int k, int sb) {
        const size_t ko = (size_t)k * 32;
        gll16(srcB + ko,                   &lds[sb + 32768 + t * 16]);
        gll16(srcB + ko + (size_t)128 * K, &lds[sb + 32768 + (t + 512) * 16]);
    };
    auto STAGE_B2 = [&](int k, int sb) {
        const size_t ko = (size_t)k * 32;
        if (t < 256)
            gll16(srcB + ko + (size_t)256 * K,
                  &lds[sb + 32768 + (t + 1024) * 16]);
    };

    f32x4 acc[8][5];
#pragma unroll
    for (int mf = 0; mf < 8; ++mf)
#pragma unroll
        for (int nf = 0; nf < 5; ++nf) {
            f32x4 z = {0.f, 0.f, 0.f, 0.f};
            acc[mf][nf] = z;
        }

    // prologue: L(0)->slab0, L(1)->slab1 (monotone order)
    STAGE_A01(0, 0); STAGE_A23(0, 0); STAGE_B01(0, 0); STAGE_B2(0, 0); SB();
    STAGE_A01(1, SLAB); STAGE_A23(1, SLAB); STAGE_B01(1, SLAB); STAGE_B2(1, SLAB);
    SB();

    for (int ks = 0; ks < NK; ++ks) {
        const int cb  = (ks % 3) * SLAB;
        const int nsb = ((ks + 2) % 3) * SLAB;
        const bool st = (ks + 2) < NK;
        if (ks + 1 < NK) {
            if (wid < 4) asm volatile("s_waitcnt vmcnt(7)" ::: "memory");
            else         asm volatile("s_waitcnt vmcnt(6)" ::: "memory");
        } else {
            asm volatile("s_waitcnt vmcnt(0)" ::: "memory");
        }
        __builtin_amdgcn_s_barrier();   // READY: slab ks staged by ALL waves

        f16x8 bv[5];
        // ---- phase 0: bv + A frags 0-1; stage A01(ks+2); 10 MFMA ----
        {
            float4v alo[2], ahi[2];
#pragma unroll
            for (int m2 = 0; m2 < 2; ++m2) {
                alo[m2] = *(const float4v*)(&lds[cb + aRd[m2]]);
                ahi[m2] = *(const float4v*)(&lds[cb + (aRd[m2] ^ 16)]);
            }
#pragma unroll
            for (int nf = 0; nf < 5; ++nf)
                bv[nf] = *(const f16x8*)(&lds[cb + bRd[nf]]);
            if (st) STAGE_A01(ks + 2, nsb);
            SB();
            asm volatile("s_waitcnt lgkmcnt(0)" ::: "memory");
            SB();                                   // rule 18
            f16x8 av[2];
#pragma unroll
            for (int m2 = 0; m2 < 2; ++m2) {
                f16x8 h;
#pragma unroll
                for (int i = 0; i < 4; ++i) {
                    h[i]     = (half_t)alo[m2][i];
                    h[i + 4] = (half_t)ahi[m2][i];
                }
                av[m2] = h;
            }
            __builtin_amdgcn_s_setprio(1);
#pragma unroll
            for (int m2 = 0; m2 < 2; ++m2)
#pragma unroll
                for (int nf = 0; nf < 5; ++nf)
                    acc[m2][nf] = __builtin_amdgcn_mfma_f32_16x16x32_f16(
                        av[m2], bv[nf], acc[m2][nf], 0, 0, 0);
            __builtin_amdgcn_s_setprio(0);
            SB();
        }
        // ---- phase 1: A frags 2-3; stage A23(ks+2); 10 MFMA ----
        {
            float4v alo[2], ahi[2];
#pragma unroll
            for (int m2 = 0; m2 < 2; ++m2) {
                alo[m2] = *(const float4v*)(&lds[cb + aRd[2 + m2]]);
                ahi[m2] = *(const float4v*)(&lds[cb + (aRd[2 + m2] ^ 16)]);
            }
            if (st) STAGE_A23(ks + 2, nsb);
            SB();
            asm volatile("s_waitcnt lgkmcnt(0)" ::: "memory");
            SB();
            f16x8 av[2];
#pragma unroll
            for (int m2 = 0; m2 < 2; ++m2) {
                f16x8 h;
#pragma unroll
                for (int i = 0; i < 4; ++i) {
                    h[i]     = (half_t)alo[m2][i];
                    h[i + 4] = (half_t)ahi[m2][i];
                }
                av[m2] = h;
            }
            __builtin_amdgcn_s_setprio(1);
#pragma unroll
            for (int m2 = 0; m2 < 2; ++m2)
#pragma unroll
                for (int nf = 0; nf < 5; ++nf)
                    acc[2 + m2][nf] = __builtin_amdgcn_mfma_f32_16x16x32_f16(
                        av[m2], bv[nf], acc[2 + m2][nf], 0, 0, 0);
            __builtin_amdgcn_s_setprio(0);
            SB();
        }
        // ---- phase 2: A frags 4-5; stage B01(ks+2); 10 MFMA ----
        {
            float4v alo[2], ahi[2];
#pragma unroll
            for (int m2 = 0; m2 < 2; ++m2) {
                alo[m2] = *(const float4v*)(&lds[cb + aRd[4 + m2]]);
                ahi[m2] = *(const float4v*)(&lds[cb + (aRd[4 + m2] ^ 16)]);
            }
            if (st) STAGE_B01(ks + 2, nsb);
            SB();
            asm volatile("s_waitcnt lgkmcnt(0)" ::: "memory");
            SB();
            f16x8 av[2];
#pragma unroll
            for (int m2 = 0; m2 < 2; ++m2) {
                f16x8 h;
#pragma unroll
                for (int i = 0; i < 4; ++i) {
                    h[i]     = (half_t)alo[m2][i];
                    h[i + 4] = (half_t)ahi[m2][i];
                }
                av[m2] = h;
            }
            __builtin_amdgcn_s_setprio(1);
#pragma unroll
            for (int m2 = 0; m2 < 2; ++m2)
#pragma unroll
                for (int nf = 0; nf < 5; ++nf)
                    acc[4 + m2][nf] = __builtin_amdgcn_mfma_f32_16x16x32_f16(
                        av[m2], bv[nf], acc[4 + m2][nf], 0, 0, 0);
            __builtin_amdgcn_s_setprio(0);
            SB();
        }
        // ---- phase 3: A frags 6-7; stage B2(ks+2); 10 MFMA ----
        {
            float4v alo[2], ahi[2];
#pragma unroll
            for (int m2 = 0; m2 < 2; ++m2) {
                alo[m2] = *(const float4v*)(&lds[cb + aRd[6 + m2]]);
                ahi[m2] = *(const float4v*)(&lds[cb + (aRd[6 + m2] ^ 16)]);
            }
            if (st) STAGE_B2(ks + 2, nsb);
            SB();
            asm volatile("s_waitcnt lgkmcnt(0)" ::: "memory");
            SB();
            f16x8 av[2];
#pragma unroll
            for (int m2 = 0; m2 < 2; ++m2) {
                f16x8 h;
#pragma unroll
                for (int i = 0; i < 4; ++i) {
                    h[i]     = (half_t)alo[m2][i];
                    h[i + 4] = (half_t)ahi[m2][i];
                }
                av[m2] = h;
            }
            __builtin_amdgcn_s_setprio(1);
#pragma unroll
            for (int m2 = 0; m2 < 2; ++m2)
#pragma unroll
                for (int nf = 0; nf < 5; ++nf)
                    acc[6 + m2][nf] = __builtin_amdgcn_mfma_f32_16x16x32_f16(
                        av[m2], bv[nf], acc[6 + m2][nf], 0, 0, 0);
            __builtin_amdgcn_s_setprio(0);
            SB();
        }
    }

    // epilogue: C/D frag col=lane&15, row=(lane>>4)*4+j
    const int crow0 = (lane >> 4) * 4;
    const int ccol  = lane & 15;
#pragma unroll
    for (int mf = 0; mf < 8; ++mf)
#pragma unroll
        for (int nf = 0; nf < 5; ++nf)
#pragma unroll
            for (int j = 0; j < 4; ++j) {
                const long row = mBase + wr * 128 + mf * 16 + crow0 + j;
                const int  col = n0 + wc * 80 + nf * 16 + ccol;
                Cout[row * HID + col] = (half_t)gelu_fast(acc[mf][nf][j]);
            }
}

// ---------- GEMM2 (+ fused layer 3), R13 ring + 3-phase interleave ----------
template <int K>
__global__ __launch_bounds__(512, 2) void gemm2_fused(
    const half_t* __restrict__ Ain, const half_t* __restrict__ Bw,
    const float* __restrict__ W3, float* __restrict__ Pout) {
    constexpr int NK     = K / 32;                    // 20
    constexpr int ABYTES = 16384;
    constexpr int SLAB   = ABYTES + 20480;
    __shared__ __align__(16) char lds[3 * SLAB];      // 108KB

    const int t = threadIdx.x, lane = t & 63, wid = t >> 6;
    const int wr = wid >> 2, wc = wid & 3;

    const int q       = (int)gridDim.x >> 3;
    const int logical = ((int)blockIdx.x & 7) * q + ((int)blockIdx.x >> 3);
    const int mb = logical >> 1, nbk = logical & 1;
    const long mBase = (long)mb * 256;
    const int  n0    = nbk * 320;

    const int rr = lane & 15, k8 = lane >> 4;

    int aBase0 = 0, bBase = 0;
    {
        const int row = wr * 128 + rr, ln = row >> 1;
        aBase0 = ln * 128 + ((((((row & 1) << 2) | k8)) ^ (ln & 7)) << 4);
        const int nrow = wc * 80 + rr, lnb = nrow >> 1;
        bBase = ABYTES + lnb * 128 +
                ((((((nrow & 1) << 2) | k8)) ^ (lnb & 7)) << 4);
    }

    const half_t* srcAh;
    {
        const int line = t >> 3, orig = (t & 7) ^ (line & 7);
        const int row = 2 * line + (orig >> 2), kq = orig & 3;
        srcAh = Ain + (mBase + row) * (long)K + kq * 8;
    }
    const half_t* srcB;
    {
        const int line = t >> 3, orig = (t & 7) ^ (line & 7);
        const int nrow = 2 * line + (orig >> 2), kq = orig & 3;
        srcB = Bw + (size_t)(n0 + nrow) * K + kq * 8;
    }

    auto STAGE_A = [&](int k, int sb) {
        const size_t ko = (size_t)k * 32;
#pragma unroll
        for (int r = 0; r < 2; ++r)
            gll16(srcAh + ko + (size_t)r * 128 * K,
                  &lds[sb + (t + r * 512) * 16]);
    };
    auto STAGE_B01 = [&](int k, int sb) {
        const size_t ko = (size_t)k * 32;
#pragma unroll
        for (int r = 0; r < 2; ++r)
            gll16(srcB + ko + (size_t)r * 128 * K,
                  &lds[sb + ABYTES + (t + r * 512) * 16]);
    };
    auto STAGE_B2 = [&](int k, int sb) {
        const size_t ko = (size_t)k * 32;
        if (t < 256)
            gll16(srcB + ko + (size_t)2 * 128 * K,
                  &lds[sb + ABYTES + (t + 1024) * 16]);
    };

    f32x4 acc[8][5];
#pragma unroll
    for (int mf = 0; mf < 8; ++mf)
#pragma unroll
        for (int nf = 0; nf < 5; ++nf) {
            f32x4 z = {0.f, 0.f, 0.f, 0.f};
            acc[mf][nf] = z;
        }

    STAGE_A(0, 0); STAGE_B01(0, 0); STAGE_B2(0, 0); SB();
    STAGE_A(1, SLAB); STAGE_B01(1, SLAB); STAGE_B2(1, SLAB); SB();

    for (int ks = 0; ks < NK; ++ks) {
        const int cb  = (ks % 3) * SLAB;
        const int nsb = ((ks + 2) % 3) * SLAB;
        const bool st = (ks + 2) < NK;
        if (ks + 1 < NK) {
            if (wid < 4) asm volatile("s_waitcnt vmcnt(5)" ::: "memory");
            else         asm volatile("s_waitcnt vmcnt(4)" ::: "memory");
        } else {
            asm volatile("s_waitcnt vmcnt(0)" ::: "memory");
        }
        __builtin_amdgcn_s_barrier();   // READY(ks)

        f16x8 bv[5];
        // ---- phase 0: bv + A frags 0-2; stage A(ks+2); 15 MFMA ----
        {
            f16x8 av[3];
#pragma unroll
            for (int m2 = 0; m2 < 3; ++m2)
                av[m2] = *(const f16x8*)(&lds[cb + aBase0 + m2 * 1024]);
#pragma unroll
            for (int nf = 0; nf < 5; ++nf)
                bv[nf] = *(const f16x8*)(&lds[cb + bBase + nf * 1024]);
            if (st) STAGE_A(ks + 2, nsb);
            SB();
            asm volatile("s_waitcnt lgkmcnt(0)" ::: "memory");
            SB();                                   // rule 18
            __builtin_amdgcn_s_setprio(1);
#pragma unroll
            for (int m2 = 0; m2 < 3; ++m2)
#pragma unroll
                for (int nf = 0; nf < 5; ++nf)
                    acc[m2][nf] = __builtin_amdgcn_mfma_f32_16x16x32_f16(
                        av[m2], bv[nf], acc[m2][nf], 0, 0, 0);
            __builtin_amdgcn_s_setprio(0);
            SB();
        }
        // ---- phase 1: A frags 3-5; stage B01(ks+2); 15 MFMA ----
        {
            f16x8 av[3];
#pragma unroll
            for (int m2 = 0; m2 < 3; ++m2)
                av[m2] = *(const f16x8*)(&lds[cb + aBase0 + (3 + m2) * 1024]);
            if (st) STAGE_B01(ks + 2, nsb);
            SB();
            asm volatile("s_waitcnt lgkmcnt(0)" ::: "memory");
            SB();
            __builtin_amdgcn_s_setprio(1);
#pragma unroll
            for (int m2 = 0; m2 < 3; ++m2)
#pragma unroll
                for (int nf = 0; nf < 5; ++nf)
                    acc[3 + m2][nf] = __builtin_amdgcn_mfma_f32_16x16x32_f16(
                        av[m2], bv[nf], acc[3 + m2][nf], 0, 0, 0);
            __builtin_amdgcn_s_setprio(0);
            SB();
        }
        // ---- phase 2: A frags 6-7; stage B2(ks+2); 10 MFMA ----
        {
            f16x8 av[2];
#pragma unroll
            for (int m2 = 0; m2 < 2; ++m2)
                av[m2] = *(const f16x8*)(&lds[cb + aBase0 + (6 + m2) * 1024]);
            if (st) STAGE_B2(ks + 2, nsb);
            SB();
            asm volatile("s_waitcnt lgkmcnt(0)" ::: "memory");
            SB();
            __builtin_amdgcn_s_setprio(1);
#pragma unroll
            for (int m2 = 0; m2 < 2; ++m2)
#pragma unroll
                for (int nf = 0; nf < 5; ++nf)
                    acc[6 + m2][nf] = __builtin_amdgcn_mfma_f32_16x16x32_f16(
                        av[m2], bv[nf], acc[6 + m2][nf], 0, 0, 0);
            __builtin_amdgcn_s_setprio(0);
            SB();
        }
    }

    // fused layer 3 epilogue (R13-proven)
    const int crow0 = (lane >> 4) * 4;
    const int ccol  = lane & 15;
    float w3[OUT_F][5];
#pragma unroll
    for (int o = 0; o < OUT_F; ++o)
#pragma unroll
        for (int nf = 0; nf < 5; ++nf)
            w3[o][nf] = W3[o * HID + n0 + wc * 80 + nf * 16 + ccol];
    float* slice = Pout + (size_t)(nbk * 4 + wc) * NBATCH * OUT_F;
#pragma unroll
    for (int mf = 0; mf < 8; ++mf)
#pragma unroll
        for (int j = 0; j < 4; ++j) {
            float p[OUT_F];
#pragma unroll
            for (int o = 0; o < OUT_F; ++o) p[o] = 0.f;
#pragma unroll
            for (int nf = 0; nf < 5; ++nf) {
                const float v = gelu_fast(acc[mf][nf][j]);
#pragma unroll
                for (int o = 0; o < OUT_F; ++o) p[o] += v * w3[o][nf];
            }
#pragma unroll
            for (int mask = 1; mask < 16; mask <<= 1)
#pragma unroll
                for (int o = 0; o < OUT_F; ++o)
                    p[o] += __shfl_xor(p[o], mask);
            float v = 0.f;
#pragma unroll
            for (int o = 0; o < OUT_F; ++o) v = (ccol == o) ? p[o] : v;
            const long row = mBase + wr * 128 + mf * 16 + crow0 + j;
            if (ccol < OUT_F) slice[row * OUT_F + ccol] = v;
        }
}

// ---------- final: out = sum of 8 partial slices ----------
__global__ void k_final(const float* __restrict__ P, float* __restrict__ out) {
    const int n = NBATCH * OUT_F;
    for (int i = blockIdx.x * blockDim.x + threadIdx.x; i < n;
         i += gridDim.x * blockDim.x) {
        float s0 = P[i]                 + P[(size_t)1 * n + i];
        float s1 = P[(size_t)2 * n + i] + P[(size_t)3 * n + i];
        float s2 = P[(size_t)4 * n + i] + P[(size_t)5 * n + i];
        float s3 = P[(size_t)6 * n + i] + P[(size_t)7 * n + i];
        out[i] = (s0 + s1) + (s2 + s3);
    }
}

// ---------- launch ----------

extern "C" void kernel_launch(void* const* d_in, const int* in_sizes, int n_in,
                              void* d_out, int out_size, void* d_ws, size_t ws_size,
                              hipStream_t stream) {
    const float* x  = (const float*)d_in[0];
    const float* W1 = (const float*)d_in[1];
    const float* W2 = (const float*)d_in[2];
    const float* W3 = (const float*)d_in[3];
    const void*  m1 = d_in[4];
    const void*  m2 = d_in[5];
    const void*  m3 = d_in[6];
    float* out = (float*)d_out;

    char* ws = (char*)d_ws;
    int*    flags = (int*)ws;
    half_t* W1h = (half_t*)(ws + 256);                      // 640*1536*2
    half_t* W2h = (half_t*)(ws + 256 + 1966080);            // 640*640*2
    float*  W3m = (float*)(ws + 256 + 1966080 + 819200);    // 25600
    half_t* h1  = (half_t*)(ws + 256 + 1966080 + 819200 + 25600);
    float*  Pp  = (float*)((char*)h1 + (size_t)NBATCH * HID * 2);  // 8*655360*4

    hipMemsetAsync(flags, 0, 8, stream);
    k_detect<<<64, 256, 0, stream>>>((const unsigned*)m1, 65536, flags);
    k_mask_all<<<1024, 256, 0, stream>>>(W1, W2, W3, m1, m2, m3, W1h, W2h, W3m, flags);

    gemm1_tall<<<512, 512, 0, stream>>>(x, W1h, h1);
    gemm2_fused<HID><<<512, 512, 0, stream>>>(h1, W2h, W3m, Pp);
    k_final<<<1024, 256, 0, stream>>>(Pp, out);
}